// Round 1
// baseline (511.815 us; speedup 1.0000x reference)
//
#include <hip/hip_runtime.h>

typedef unsigned short u16;
typedef short bf16x8 __attribute__((ext_vector_type(8)));
typedef float f32x4 __attribute__((ext_vector_type(4)));

#define MFMA_BF16(a, b, c) __builtin_amdgcn_mfma_f32_16x16x32_bf16((a), (b), (c), 0, 0, 0)

__device__ __forceinline__ u16 f2bf(float f) {
  union { float f; unsigned int u; } cv;
  cv.f = f;
  unsigned int u = cv.u + 0x7fffu + ((cv.u >> 16) & 1u);
  return (u16)(u >> 16);
}

// ---------------- LayerNorm over x rows (2048 wide), write bf16 ----------------
__global__ __launch_bounds__(256) void ln_x_kernel(
    const float* __restrict__ x, const float* __restrict__ w,
    const float* __restrict__ b, u16* __restrict__ outp)
{
  const int row = blockIdx.x;
  const int tid = threadIdx.x;
  const float4* xr = (const float4*)(x + (size_t)row * 2048);
  float4 v0 = xr[tid];
  float4 v1 = xr[tid + 256];
  float sum = v0.x + v0.y + v0.z + v0.w + v1.x + v1.y + v1.z + v1.w;
  float sq  = v0.x*v0.x + v0.y*v0.y + v0.z*v0.z + v0.w*v0.w
            + v1.x*v1.x + v1.y*v1.y + v1.z*v1.z + v1.w*v1.w;
  #pragma unroll
  for (int off = 32; off > 0; off >>= 1) {
    sum += __shfl_xor(sum, off);
    sq  += __shfl_xor(sq, off);
  }
  __shared__ float red[8];
  if ((tid & 63) == 0) { red[tid >> 6] = sum; red[(tid >> 6) + 4] = sq; }
  __syncthreads();
  sum = red[0] + red[1] + red[2] + red[3];
  sq  = red[4] + red[5] + red[6] + red[7];
  const float mean = sum * (1.0f / 2048.0f);
  const float var  = sq * (1.0f / 2048.0f) - mean * mean;
  const float rstd = rsqrtf(var + 1e-5f);
  const float4* w4 = (const float4*)w;
  const float4* b4 = (const float4*)b;
  ushort4* orow = (ushort4*)(outp + (size_t)row * 2048);
  #pragma unroll
  for (int j = 0; j < 2; ++j) {
    const int idx = tid + j * 256;
    const float4 v = j ? v1 : v0;
    const float4 ww = w4[idx];
    const float4 bb = b4[idx];
    ushort4 o;
    o.x = f2bf((v.x - mean) * rstd * ww.x + bb.x);
    o.y = f2bf((v.y - mean) * rstd * ww.y + bb.y);
    o.z = f2bf((v.z - mean) * rstd * ww.z + bb.z);
    o.w = f2bf((v.w - mean) * rstd * ww.w + bb.w);
    orow[idx] = o;
  }
}

// ---------------- LayerNorm over latents + AdaLN modulation, write bf16 ----------------
__global__ __launch_bounds__(256) void ln_lat_kernel(
    const float* __restrict__ latents, const float* __restrict__ t_emb,
    const float* __restrict__ ssg, u16* __restrict__ outp)
{
  const int row  = blockIdx.x;     // b*512 + l
  const int bidx = row >> 9;
  const int tid  = threadIdx.x;
  const float4* xr = (const float4*)(latents + (size_t)row * 2048);
  float4 v0 = xr[tid];
  float4 v1 = xr[tid + 256];
  float sum = v0.x + v0.y + v0.z + v0.w + v1.x + v1.y + v1.z + v1.w;
  float sq  = v0.x*v0.x + v0.y*v0.y + v0.z*v0.z + v0.w*v0.w
            + v1.x*v1.x + v1.y*v1.y + v1.z*v1.z + v1.w*v1.w;
  #pragma unroll
  for (int off = 32; off > 0; off >>= 1) {
    sum += __shfl_xor(sum, off);
    sq  += __shfl_xor(sq, off);
  }
  __shared__ float red[8];
  if ((tid & 63) == 0) { red[tid >> 6] = sum; red[(tid >> 6) + 4] = sq; }
  __syncthreads();
  sum = red[0] + red[1] + red[2] + red[3];
  sq  = red[4] + red[5] + red[6] + red[7];
  const float mean = sum * (1.0f / 2048.0f);
  const float var  = sq * (1.0f / 2048.0f) - mean * mean;
  const float rstd = rsqrtf(var + 1e-5f);
  const float4* te = (const float4*)(t_emb + (size_t)bidx * 3 * 2048);
  const float4* sg = (const float4*)ssg;
  ushort4* orow = (ushort4*)(outp + (size_t)row * 2048);
  #pragma unroll
  for (int j = 0; j < 2; ++j) {
    const int idx = tid + j * 256;
    const float4 v = j ? v1 : v0;
    const float4 t0 = te[idx];        // shift row
    const float4 t1 = te[512 + idx];  // scale row
    const float4 s0 = sg[idx];
    const float4 s1 = sg[512 + idx];
    ushort4 o;
    o.x = f2bf(((v.x - mean) * rstd) * (1.0f + t1.x + s1.x) + (t0.x + s0.x));
    o.y = f2bf(((v.y - mean) * rstd) * (1.0f + t1.y + s1.y) + (t0.y + s0.y));
    o.z = f2bf(((v.z - mean) * rstd) * (1.0f + t1.z + s1.z) + (t0.z + s0.z));
    o.w = f2bf(((v.w - mean) * rstd) * (1.0f + t1.w + s1.w) + (t0.w + s0.w));
    orow[idx] = o;
  }
}

// ---------------- fp32 (R x C) -> bf16 transposed (C x R) ----------------
__global__ __launch_bounds__(256) void transpose_bf16_kernel(
    const float* __restrict__ in, u16* __restrict__ outp, int R, int C)
{
  __shared__ float tile[32][33];
  const int tx = threadIdx.x & 31;
  const int ty = threadIdx.x >> 5;   // 0..7
  const int c0 = blockIdx.x * 32;
  const int r0 = blockIdx.y * 32;
  #pragma unroll
  for (int i = 0; i < 4; ++i)
    tile[ty + i * 8][tx] = in[(size_t)(r0 + ty + i * 8) * C + c0 + tx];
  __syncthreads();
  #pragma unroll
  for (int i = 0; i < 4; ++i)
    outp[(size_t)(c0 + ty + i * 8) * R + r0 + tx] = f2bf(tile[tx][ty + i * 8]);
}

// ---------------- bf16 MFMA GEMM: C = A (MxK) * BT (NxK)^T + bias, fused epilogues ----------------
// mode 0: q proj    -> out_q  bf16 (B,H,L,C)
// mode 1: kv proj   -> out_k  bf16 (B,H,K,C), out_vT bf16 (B,H,C,K)
// mode 2: out proj  -> out_f  fp32 (B*L, D), fused * gate
__global__ __launch_bounds__(256) void gemm_bf16_kernel(
    const u16* __restrict__ A, const u16* __restrict__ BT,
    int M, int N, int Kd, int mode,
    const float* __restrict__ bias,
    u16* __restrict__ out_q, u16* __restrict__ out_k, u16* __restrict__ out_vT,
    float* __restrict__ out_f,
    const float* __restrict__ t_emb, const float* __restrict__ ssg)
{
  __shared__ u16 As[128][40];   // stride 40 elem = 80B: 16B-aligned rows, ~2-way banks
  __shared__ u16 Bs[128][40];
  const int tid  = threadIdx.x;
  const int lane = tid & 63;
  const int wv   = tid >> 6;
  const int wm   = wv & 1, wn = wv >> 1;
  const int quad = lane >> 4, lq = lane & 15;
  const int m0 = blockIdx.y * 128, n0 = blockIdx.x * 128;

  f32x4 acc[4][4];
  #pragma unroll
  for (int i = 0; i < 4; ++i)
    #pragma unroll
    for (int j = 0; j < 4; ++j)
      acc[i][j] = (f32x4){0.f, 0.f, 0.f, 0.f};

  const int r  = tid >> 1;
  const int hf = (tid & 1) * 16;  // element offset within 32-wide k tile
  const u16* gA = A  + (size_t)(m0 + r) * Kd + hf;
  const u16* gB = BT + (size_t)(n0 + r) * Kd + hf;

  for (int k0 = 0; k0 < Kd; k0 += 32) {
    const uint4 a0 = *(const uint4*)(gA + k0);
    const uint4 a1 = *(const uint4*)(gA + k0 + 8);
    const uint4 b0 = *(const uint4*)(gB + k0);
    const uint4 b1 = *(const uint4*)(gB + k0 + 8);
    __syncthreads();                 // previous iteration's LDS reads done
    *(uint4*)&As[r][hf]     = a0;
    *(uint4*)&As[r][hf + 8] = a1;
    *(uint4*)&Bs[r][hf]     = b0;
    *(uint4*)&Bs[r][hf + 8] = b1;
    __syncthreads();
    bf16x8 av[4], bv[4];
    #pragma unroll
    for (int i = 0; i < 4; ++i)
      av[i] = *(const bf16x8*)&As[wm * 64 + i * 16 + lq][quad * 8];
    #pragma unroll
    for (int j = 0; j < 4; ++j)
      bv[j] = *(const bf16x8*)&Bs[wn * 64 + j * 16 + lq][quad * 8];
    #pragma unroll
    for (int i = 0; i < 4; ++i)
      #pragma unroll
      for (int j = 0; j < 4; ++j)
        acc[i][j] = MFMA_BF16(av[i], bv[j], acc[i][j]);
  }

  // epilogue; C/D layout: col = lane&15, row = quad*4 + reg
  #pragma unroll
  for (int i = 0; i < 4; ++i) {
    const int mlb = m0 + wm * 64 + i * 16 + quad * 4;
    #pragma unroll
    for (int j = 0; j < 4; ++j) {
      const int n = n0 + wn * 64 + j * 16 + lq;
      const float bs = bias[n];
      if (mode == 0) {
        const int h = n >> 7, c = n & 127;
        #pragma unroll
        for (int rr = 0; rr < 4; ++rr) {
          const int m = mlb + rr;
          const int bb = m >> 9, l = m & 511;
          out_q[((size_t)(bb * 16 + h) * 512 + l) * 128 + c] = f2bf(acc[i][j][rr] + bs);
        }
      } else if (mode == 1) {
        if (n < 2048) {
          const int h = n >> 7, c = n & 127;
          #pragma unroll
          for (int rr = 0; rr < 4; ++rr) {
            const int m = mlb + rr;
            const int bb = m >> 10, kk = m & 1023;
            out_k[((size_t)(bb * 16 + h) * 1024 + kk) * 128 + c] = f2bf(acc[i][j][rr] + bs);
          }
        } else {
          const int n2 = n - 2048;
          const int h = n2 >> 7, c = n2 & 127;
          #pragma unroll
          for (int rr = 0; rr < 4; ++rr) {
            const int m = mlb + rr;
            const int bb = m >> 10, kk = m & 1023;
            out_vT[((size_t)(bb * 16 + h) * 128 + c) * 1024 + kk] = f2bf(acc[i][j][rr] + bs);
          }
        }
      } else {
        #pragma unroll
        for (int rr = 0; rr < 4; ++rr) {
          const int m = mlb + rr;
          const int bb = m >> 9;
          const float g = t_emb[((size_t)bb * 3 + 2) * 2048 + n] + ssg[2 * 2048 + n];
          out_f[(size_t)m * 2048 + n] = (acc[i][j][rr] + bs) * g;
        }
      }
    }
  }
}

// ---------------- flash attention: per (b,h, 64-row q tile) ----------------
#define ATT_SCALE 0.08838834764831845f  // 1/sqrt(128)

__global__ __launch_bounds__(256) void attn_kernel(
    const u16* __restrict__ qb, const u16* __restrict__ kb,
    const u16* __restrict__ vT, const int* __restrict__ k_lens,
    const int* __restrict__ q_lens, u16* __restrict__ ao)
{
  __shared__ u16 p_lds[64][72];   // row stride 144B (16B-aligned, 2-way banks)
  const int tid  = threadIdx.x;
  const int w    = tid >> 6;
  const int lane = tid & 63;
  const int quad = lane >> 4, lq = lane & 15;
  const int bh = blockIdx.y;           // b*16 + h
  const int b  = bh >> 4;
  const int l0 = blockIdx.x * 64;
  const int kl = k_lens[b];
  const int ql = q_lens[b];

  // Q fragments in registers (A-operand layout): rows w*16+lq, C-dim split into 4 k-steps
  bf16x8 qf[4];
  {
    const u16* qp = qb + ((size_t)bh * 512 + l0 + w * 16 + lq) * 128 + quad * 8;
    #pragma unroll
    for (int ks = 0; ks < 4; ++ks)
      qf[ks] = *(const bf16x8*)(qp + ks * 32);
  }

  f32x4 o[8];
  #pragma unroll
  for (int j = 0; j < 8; ++j) o[j] = (f32x4){0.f, 0.f, 0.f, 0.f};
  float mrun[4], lrun[4];
  #pragma unroll
  for (int rr = 0; rr < 4; ++rr) { mrun[rr] = -__builtin_inff(); lrun[rr] = 0.f; }

  const int nkt = (kl + 63) >> 6;
  for (int kt = 0; kt < nkt; ++kt) {
    const int k0 = kt * 64;
    // S = Q K^T  (rows = q, cols = keys)
    f32x4 s[4];
    const u16* kp = kb + ((size_t)bh * 1024 + k0) * 128 + quad * 8;
    #pragma unroll
    for (int ct = 0; ct < 4; ++ct) {
      s[ct] = (f32x4){0.f, 0.f, 0.f, 0.f};
      const u16* kpp = kp + (size_t)(ct * 16 + lq) * 128;
      #pragma unroll
      for (int ks = 0; ks < 4; ++ks) {
        const bf16x8 kf = *(const bf16x8*)(kpp + ks * 32);
        s[ct] = MFMA_BF16(qf[ks], kf, s[ct]);
      }
    }
    // scale + key mask
    #pragma unroll
    for (int ct = 0; ct < 4; ++ct) {
      const bool valid = (k0 + ct * 16 + lq) < kl;
      #pragma unroll
      for (int rr = 0; rr < 4; ++rr) {
        const float sv = s[ct][rr] * ATT_SCALE;
        s[ct][rr] = valid ? sv : -__builtin_inff();
      }
    }
    // online softmax: row max over 4 col-tiles then across 16-lane group
    float mnew[4], alpha[4], rs[4];
    #pragma unroll
    for (int rr = 0; rr < 4; ++rr) {
      float tm = fmaxf(fmaxf(s[0][rr], s[1][rr]), fmaxf(s[2][rr], s[3][rr]));
      tm = fmaxf(tm, __shfl_xor(tm, 1));
      tm = fmaxf(tm, __shfl_xor(tm, 2));
      tm = fmaxf(tm, __shfl_xor(tm, 4));
      tm = fmaxf(tm, __shfl_xor(tm, 8));
      const float mn = fmaxf(mrun[rr], tm);
      alpha[rr] = __expf(mrun[rr] - mn);
      mrun[rr] = mn;
      mnew[rr] = mn;
      rs[rr] = 0.f;
    }
    #pragma unroll
    for (int ct = 0; ct < 4; ++ct)
      #pragma unroll
      for (int rr = 0; rr < 4; ++rr) {
        const float p = __expf(s[ct][rr] - mnew[rr]);
        s[ct][rr] = p;
        rs[rr] += p;
      }
    #pragma unroll
    for (int rr = 0; rr < 4; ++rr) {
      float t = rs[rr];
      t += __shfl_xor(t, 1);
      t += __shfl_xor(t, 2);
      t += __shfl_xor(t, 4);
      t += __shfl_xor(t, 8);
      lrun[rr] = lrun[rr] * alpha[rr] + t;
    }
    #pragma unroll
    for (int j = 0; j < 8; ++j)
      #pragma unroll
      for (int rr = 0; rr < 4; ++rr)
        o[j][rr] *= alpha[rr];

    // P: C/D layout -> A layout round-trip through wave-private LDS rows
    #pragma unroll
    for (int ct = 0; ct < 4; ++ct)
      #pragma unroll
      for (int rr = 0; rr < 4; ++rr)
        p_lds[w * 16 + quad * 4 + rr][ct * 16 + lq] = f2bf(s[ct][rr]);

    bf16x8 pf[2];
    pf[0] = *(const bf16x8*)&p_lds[w * 16 + lq][quad * 8];
    pf[1] = *(const bf16x8*)&p_lds[w * 16 + lq][32 + quad * 8];

    // O += P V   (V^T stored (B,H,C,K): contiguous along keys)
    const u16* vp = vT + (size_t)bh * 128 * 1024 + k0 + quad * 8;
    #pragma unroll
    for (int j = 0; j < 8; ++j) {
      #pragma unroll
      for (int ks2 = 0; ks2 < 2; ++ks2) {
        const bf16x8 vf = *(const bf16x8*)(vp + (size_t)(j * 16 + lq) * 1024 + ks2 * 32);
        o[j] = MFMA_BF16(pf[ks2], vf, o[j]);
      }
    }
  }

  // normalize + q mask, write attn_out bf16 (B, L, D)
  const int h = bh & 15;
  #pragma unroll
  for (int rr = 0; rr < 4; ++rr) {
    const int row = l0 + w * 16 + quad * 4 + rr;
    const float inv = (row < ql) ? (1.0f / lrun[rr]) : 0.0f;
    u16* op = ao + ((size_t)b * 512 + row) * 2048 + h * 128 + lq;
    #pragma unroll
    for (int j = 0; j < 8; ++j)
      op[j * 16] = f2bf(o[j][rr] * inv);
  }
}

extern "C" void kernel_launch(void* const* d_in, const int* in_sizes, int n_in,
                              void* d_out, int out_size, void* d_ws, size_t ws_size,
                              hipStream_t stream) {
  (void)in_sizes; (void)n_in; (void)out_size; (void)ws_size;
  const float* x       = (const float*)d_in[0];
  const float* latents = (const float*)d_in[1];
  const float* t_emb   = (const float*)d_in[2];
  const int*   q_lens  = (const int*)d_in[3];
  const int*   k_lens  = (const int*)d_in[4];
  const float* ln_w    = (const float*)d_in[5];
  const float* ln_b    = (const float*)d_in[6];
  const float* ssg     = (const float*)d_in[7];
  const float* Wq      = (const float*)d_in[8];
  const float* bq      = (const float*)d_in[9];
  const float* Wkv     = (const float*)d_in[10];
  const float* bkv     = (const float*)d_in[11];
  const float* Wo      = (const float*)d_in[12];
  const float* bo      = (const float*)d_in[13];
  float* out = (float*)d_out;

  u16* ws = (u16*)d_ws;
  const size_t MEG = (size_t)1 << 20;      // elements
  u16* WqT  = ws;                 //  4M elems: (2048 x 2048) bf16, N-major
  u16* WoT  = ws + 4  * MEG;      //  4M
  u16* WkvT = ws + 8  * MEG;      //  8M: (4096 x 2048)
  u16* xk   = ws + 16 * MEG;      //  8M: (B*K, 2048)
  u16* lat  = ws + 24 * MEG;      //  4M: (B*L, 2048)
  u16* qb   = ws + 28 * MEG;      //  4M: (B,H,L,C)
  u16* kbuf = ws + 32 * MEG;      //  8M: (B,H,K,C)
  u16* vTb  = ws + 40 * MEG;      //  8M: (B,H,C,K)
  u16* aob  = ws + 48 * MEG;      //  4M: (B*L, 2048)
  // total 52M elems = 104 MB

  // LN stages
  ln_x_kernel<<<dim3(4096), dim3(256), 0, stream>>>(x, ln_w, ln_b, xk);
  ln_lat_kernel<<<dim3(2048), dim3(256), 0, stream>>>(latents, t_emb, ssg, lat);

  // weight transpose + bf16 convert
  transpose_bf16_kernel<<<dim3(64, 64),  dim3(256), 0, stream>>>(Wq,  WqT,  2048, 2048);
  transpose_bf16_kernel<<<dim3(64, 64),  dim3(256), 0, stream>>>(Wo,  WoT,  2048, 2048);
  transpose_bf16_kernel<<<dim3(128, 64), dim3(256), 0, stream>>>(Wkv, WkvT, 2048, 4096);

  // q = lat @ Wq + bq  -> (B,H,L,C)
  gemm_bf16_kernel<<<dim3(16, 16), dim3(256), 0, stream>>>(
      lat, WqT, 2048, 2048, 2048, 0, bq, qb, nullptr, nullptr, nullptr, nullptr, nullptr);
  // kv = xk @ Wkv + bkv -> k (B,H,K,C), v^T (B,H,C,K)
  gemm_bf16_kernel<<<dim3(32, 32), dim3(256), 0, stream>>>(
      xk, WkvT, 4096, 4096, 2048, 1, bkv, nullptr, kbuf, vTb, nullptr, nullptr, nullptr);

  // flash attention
  attn_kernel<<<dim3(8, 64), dim3(256), 0, stream>>>(qb, kbuf, vTb, k_lens, q_lens, aob);

  // out = (attn_out @ Wo + bo) * gate
  gemm_bf16_kernel<<<dim3(16, 16), dim3(256), 0, stream>>>(
      aob, WoT, 2048, 2048, 2048, 2, bo, nullptr, nullptr, nullptr, out, t_emb, ssg);
}

// Round 2
// 483.849 us; speedup vs baseline: 1.0578x; 1.0578x over previous
//
#include <hip/hip_runtime.h>

typedef unsigned short u16;
typedef short bf16x8 __attribute__((ext_vector_type(8)));
typedef float f32x4 __attribute__((ext_vector_type(4)));

#define MFMA_BF16(a, b, c) __builtin_amdgcn_mfma_f32_16x16x32_bf16((a), (b), (c), 0, 0, 0)

__device__ __forceinline__ u16 f2bf(float f) {
  union { float f; unsigned int u; } cv;
  cv.f = f;
  unsigned int u = cv.u + 0x7fffu + ((cv.u >> 16) & 1u);
  return (u16)(u >> 16);
}

// async global -> LDS, 16B per lane. LDS dest = wave-uniform base + lane*16B.
__device__ __forceinline__ void async16(const u16* g, u16* l) {
  __builtin_amdgcn_global_load_lds(
      (const __attribute__((address_space(1))) unsigned int*)g,
      (__attribute__((address_space(3))) unsigned int*)l, 16, 0, 0);
}

// ---------------- LayerNorm over x rows (2048 wide), write bf16 ----------------
__global__ __launch_bounds__(256) void ln_x_kernel(
    const float* __restrict__ x, const float* __restrict__ w,
    const float* __restrict__ b, u16* __restrict__ outp)
{
  const int row = blockIdx.x;
  const int tid = threadIdx.x;
  const float4* xr = (const float4*)(x + (size_t)row * 2048);
  float4 v0 = xr[tid];
  float4 v1 = xr[tid + 256];
  float sum = v0.x + v0.y + v0.z + v0.w + v1.x + v1.y + v1.z + v1.w;
  float sq  = v0.x*v0.x + v0.y*v0.y + v0.z*v0.z + v0.w*v0.w
            + v1.x*v1.x + v1.y*v1.y + v1.z*v1.z + v1.w*v1.w;
  #pragma unroll
  for (int off = 32; off > 0; off >>= 1) {
    sum += __shfl_xor(sum, off);
    sq  += __shfl_xor(sq, off);
  }
  __shared__ float red[8];
  if ((tid & 63) == 0) { red[tid >> 6] = sum; red[(tid >> 6) + 4] = sq; }
  __syncthreads();
  sum = red[0] + red[1] + red[2] + red[3];
  sq  = red[4] + red[5] + red[6] + red[7];
  const float mean = sum * (1.0f / 2048.0f);
  const float var  = sq * (1.0f / 2048.0f) - mean * mean;
  const float rstd = rsqrtf(var + 1e-5f);
  const float4* w4 = (const float4*)w;
  const float4* b4 = (const float4*)b;
  ushort4* orow = (ushort4*)(outp + (size_t)row * 2048);
  #pragma unroll
  for (int j = 0; j < 2; ++j) {
    const int idx = tid + j * 256;
    const float4 v = j ? v1 : v0;
    const float4 ww = w4[idx];
    const float4 bb = b4[idx];
    ushort4 o;
    o.x = f2bf((v.x - mean) * rstd * ww.x + bb.x);
    o.y = f2bf((v.y - mean) * rstd * ww.y + bb.y);
    o.z = f2bf((v.z - mean) * rstd * ww.z + bb.z);
    o.w = f2bf((v.w - mean) * rstd * ww.w + bb.w);
    orow[idx] = o;
  }
}

// ---------------- LayerNorm over latents + AdaLN modulation, write bf16 ----------------
__global__ __launch_bounds__(256) void ln_lat_kernel(
    const float* __restrict__ latents, const float* __restrict__ t_emb,
    const float* __restrict__ ssg, u16* __restrict__ outp)
{
  const int row  = blockIdx.x;     // b*512 + l
  const int bidx = row >> 9;
  const int tid  = threadIdx.x;
  const float4* xr = (const float4*)(latents + (size_t)row * 2048);
  float4 v0 = xr[tid];
  float4 v1 = xr[tid + 256];
  float sum = v0.x + v0.y + v0.z + v0.w + v1.x + v1.y + v1.z + v1.w;
  float sq  = v0.x*v0.x + v0.y*v0.y + v0.z*v0.z + v0.w*v0.w
            + v1.x*v1.x + v1.y*v1.y + v1.z*v1.z + v1.w*v1.w;
  #pragma unroll
  for (int off = 32; off > 0; off >>= 1) {
    sum += __shfl_xor(sum, off);
    sq  += __shfl_xor(sq, off);
  }
  __shared__ float red[8];
  if ((tid & 63) == 0) { red[tid >> 6] = sum; red[(tid >> 6) + 4] = sq; }
  __syncthreads();
  sum = red[0] + red[1] + red[2] + red[3];
  sq  = red[4] + red[5] + red[6] + red[7];
  const float mean = sum * (1.0f / 2048.0f);
  const float var  = sq * (1.0f / 2048.0f) - mean * mean;
  const float rstd = rsqrtf(var + 1e-5f);
  const float4* te = (const float4*)(t_emb + (size_t)bidx * 3 * 2048);
  const float4* sg = (const float4*)ssg;
  ushort4* orow = (ushort4*)(outp + (size_t)row * 2048);
  #pragma unroll
  for (int j = 0; j < 2; ++j) {
    const int idx = tid + j * 256;
    const float4 v = j ? v1 : v0;
    const float4 t0 = te[idx];        // shift row
    const float4 t1 = te[512 + idx];  // scale row
    const float4 s0 = sg[idx];
    const float4 s1 = sg[512 + idx];
    ushort4 o;
    o.x = f2bf(((v.x - mean) * rstd) * (1.0f + t1.x + s1.x) + (t0.x + s0.x));
    o.y = f2bf(((v.y - mean) * rstd) * (1.0f + t1.y + s1.y) + (t0.y + s0.y));
    o.z = f2bf(((v.z - mean) * rstd) * (1.0f + t1.z + s1.z) + (t0.z + s0.z));
    o.w = f2bf(((v.w - mean) * rstd) * (1.0f + t1.w + s1.w) + (t0.w + s0.w));
    orow[idx] = o;
  }
}

// ---------------- fp32 (R x C) -> bf16 transposed (C x R) ----------------
__global__ __launch_bounds__(256) void transpose_bf16_kernel(
    const float* __restrict__ in, u16* __restrict__ outp, int R, int C)
{
  __shared__ float tile[32][33];
  const int tx = threadIdx.x & 31;
  const int ty = threadIdx.x >> 5;   // 0..7
  const int c0 = blockIdx.x * 32;
  const int r0 = blockIdx.y * 32;
  #pragma unroll
  for (int i = 0; i < 4; ++i)
    tile[ty + i * 8][tx] = in[(size_t)(r0 + ty + i * 8) * C + c0 + tx];
  __syncthreads();
  #pragma unroll
  for (int i = 0; i < 4; ++i)
    outp[(size_t)(c0 + ty + i * 8) * R + r0 + tx] = f2bf(tile[tx][ty + i * 8]);
}

// ---------------- bf16 MFMA GEMM (global_load_lds staging, m97 structure) ----------------
// C = A (MxK) * BT (NxK)^T + bias, fused epilogues:
// mode 0: q proj    -> out_q  bf16 (B,H,L,C)
// mode 1: kv proj   -> out_k  bf16 (B,H,K,C), out_vT bf16 (B,H,C,K)
// mode 2: out proj  -> out_f  fp32 (B*L, D), fused * gate
__global__ __launch_bounds__(256) void gemm_bf16_kernel(
    const u16* __restrict__ A, const u16* __restrict__ BT,
    int M, int N, int Kd, int mode,
    const float* __restrict__ bias,
    u16* __restrict__ out_q, u16* __restrict__ out_k, u16* __restrict__ out_vT,
    float* __restrict__ out_f,
    const float* __restrict__ t_emb, const float* __restrict__ ssg)
{
  // UNPADDED: global_load_lds writes base + lane*16B; layout must be contiguous.
  __shared__ u16 As[128][32];
  __shared__ u16 Bs[128][32];
  const int tid  = threadIdx.x;
  const int lane = tid & 63;
  const int wv   = tid >> 6;
  const int wm   = wv & 1, wn = wv >> 1;
  const int quad = lane >> 4, lq = lane & 15;
  const int m0 = blockIdx.y * 128, n0 = blockIdx.x * 128;

  f32x4 acc[4][4];
  #pragma unroll
  for (int i = 0; i < 4; ++i)
    #pragma unroll
    for (int j = 0; j < 4; ++j)
      acc[i][j] = (f32x4){0.f, 0.f, 0.f, 0.f};

  // staging map: wave w call c -> rows [w*32+c*16, +16), lane i -> row +i/4, col (i&3)*8
  const int srow = wv * 32 + (lane >> 2);
  const int scol = (lane & 3) * 8;
  const u16* gA0 = A  + (size_t)(m0 + srow) * Kd + scol;
  const u16* gA1 = gA0 + (size_t)16 * Kd;
  const u16* gB0 = BT + (size_t)(n0 + srow) * Kd + scol;
  const u16* gB1 = gB0 + (size_t)16 * Kd;
  u16* lA0 = &As[wv * 32][0];
  u16* lA1 = &As[wv * 32 + 16][0];
  u16* lB0 = &Bs[wv * 32][0];
  u16* lB1 = &Bs[wv * 32 + 16][0];

  for (int k0 = 0; k0 < Kd; k0 += 32) {
    __syncthreads();                 // prior iteration's LDS reads done
    async16(gA0 + k0, lA0);
    async16(gA1 + k0, lA1);
    async16(gB0 + k0, lB0);
    async16(gB1 + k0, lB1);
    __syncthreads();                 // vmcnt(0) drain + barrier
    bf16x8 av[4], bv[4];
    #pragma unroll
    for (int i = 0; i < 4; ++i)
      av[i] = *(const bf16x8*)&As[wm * 64 + i * 16 + lq][quad * 8];
    #pragma unroll
    for (int j = 0; j < 4; ++j)
      bv[j] = *(const bf16x8*)&Bs[wn * 64 + j * 16 + lq][quad * 8];
    #pragma unroll
    for (int i = 0; i < 4; ++i)
      #pragma unroll
      for (int j = 0; j < 4; ++j)
        acc[i][j] = MFMA_BF16(av[i], bv[j], acc[i][j]);
  }

  // epilogue; C/D layout: col = lane&15, row = quad*4 + reg
  #pragma unroll
  for (int i = 0; i < 4; ++i) {
    const int mlb = m0 + wm * 64 + i * 16 + quad * 4;
    #pragma unroll
    for (int j = 0; j < 4; ++j) {
      const int n = n0 + wn * 64 + j * 16 + lq;
      const float bs = bias[n];
      if (mode == 0) {
        const int h = n >> 7, c = n & 127;
        #pragma unroll
        for (int rr = 0; rr < 4; ++rr) {
          const int m = mlb + rr;
          const int bb = m >> 9, l = m & 511;
          out_q[((size_t)(bb * 16 + h) * 512 + l) * 128 + c] = f2bf(acc[i][j][rr] + bs);
        }
      } else if (mode == 1) {
        if (n < 2048) {
          const int h = n >> 7, c = n & 127;
          #pragma unroll
          for (int rr = 0; rr < 4; ++rr) {
            const int m = mlb + rr;
            const int bb = m >> 10, kk = m & 1023;
            out_k[((size_t)(bb * 16 + h) * 1024 + kk) * 128 + c] = f2bf(acc[i][j][rr] + bs);
          }
        } else {
          const int n2 = n - 2048;
          const int h = n2 >> 7, c = n2 & 127;
          #pragma unroll
          for (int rr = 0; rr < 4; ++rr) {
            const int m = mlb + rr;
            const int bb = m >> 10, kk = m & 1023;
            out_vT[((size_t)(bb * 16 + h) * 128 + c) * 1024 + kk] = f2bf(acc[i][j][rr] + bs);
          }
        }
      } else {
        #pragma unroll
        for (int rr = 0; rr < 4; ++rr) {
          const int m = mlb + rr;
          const int bb = m >> 9;
          const float g = t_emb[((size_t)bb * 3 + 2) * 2048 + n] + ssg[2 * 2048 + n];
          out_f[(size_t)m * 2048 + n] = (acc[i][j][rr] + bs) * g;
        }
      }
    }
  }
}

// ---------------- flash attention: per (b,h, 64-row q tile) ----------------
#define ATT_SCALE 0.08838834764831845f  // 1/sqrt(128)

__global__ __launch_bounds__(256) void attn_kernel(
    const u16* __restrict__ qb, const u16* __restrict__ kb,
    const u16* __restrict__ vT, const int* __restrict__ k_lens,
    const int* __restrict__ q_lens, u16* __restrict__ ao)
{
  __shared__ u16 p_lds[64][72];   // row stride 144B (16B-aligned, 2-way banks)
  const int tid  = threadIdx.x;
  const int w    = tid >> 6;
  const int lane = tid & 63;
  const int quad = lane >> 4, lq = lane & 15;
  const int bh = blockIdx.y;           // b*16 + h
  const int b  = bh >> 4;
  const int l0 = blockIdx.x * 64;
  const int kl = k_lens[b];
  const int ql = q_lens[b];

  bf16x8 qf[4];
  {
    const u16* qp = qb + ((size_t)bh * 512 + l0 + w * 16 + lq) * 128 + quad * 8;
    #pragma unroll
    for (int ks = 0; ks < 4; ++ks)
      qf[ks] = *(const bf16x8*)(qp + ks * 32);
  }

  f32x4 o[8];
  #pragma unroll
  for (int j = 0; j < 8; ++j) o[j] = (f32x4){0.f, 0.f, 0.f, 0.f};
  float mrun[4], lrun[4];
  #pragma unroll
  for (int rr = 0; rr < 4; ++rr) { mrun[rr] = -__builtin_inff(); lrun[rr] = 0.f; }

  const int nkt = (kl + 63) >> 6;
  for (int kt = 0; kt < nkt; ++kt) {
    const int k0 = kt * 64;
    f32x4 s[4];
    const u16* kp = kb + ((size_t)bh * 1024 + k0) * 128 + quad * 8;
    #pragma unroll
    for (int ct = 0; ct < 4; ++ct) {
      s[ct] = (f32x4){0.f, 0.f, 0.f, 0.f};
      const u16* kpp = kp + (size_t)(ct * 16 + lq) * 128;
      #pragma unroll
      for (int ks = 0; ks < 4; ++ks) {
        const bf16x8 kf = *(const bf16x8*)(kpp + ks * 32);
        s[ct] = MFMA_BF16(qf[ks], kf, s[ct]);
      }
    }
    #pragma unroll
    for (int ct = 0; ct < 4; ++ct) {
      const bool valid = (k0 + ct * 16 + lq) < kl;
      #pragma unroll
      for (int rr = 0; rr < 4; ++rr) {
        const float sv = s[ct][rr] * ATT_SCALE;
        s[ct][rr] = valid ? sv : -__builtin_inff();
      }
    }
    float mnew[4], alpha[4], rs[4];
    #pragma unroll
    for (int rr = 0; rr < 4; ++rr) {
      float tm = fmaxf(fmaxf(s[0][rr], s[1][rr]), fmaxf(s[2][rr], s[3][rr]));
      tm = fmaxf(tm, __shfl_xor(tm, 1));
      tm = fmaxf(tm, __shfl_xor(tm, 2));
      tm = fmaxf(tm, __shfl_xor(tm, 4));
      tm = fmaxf(tm, __shfl_xor(tm, 8));
      const float mn = fmaxf(mrun[rr], tm);
      alpha[rr] = __expf(mrun[rr] - mn);
      mrun[rr] = mn;
      mnew[rr] = mn;
      rs[rr] = 0.f;
    }
    #pragma unroll
    for (int ct = 0; ct < 4; ++ct)
      #pragma unroll
      for (int rr = 0; rr < 4; ++rr) {
        const float p = __expf(s[ct][rr] - mnew[rr]);
        s[ct][rr] = p;
        rs[rr] += p;
      }
    #pragma unroll
    for (int rr = 0; rr < 4; ++rr) {
      float t = rs[rr];
      t += __shfl_xor(t, 1);
      t += __shfl_xor(t, 2);
      t += __shfl_xor(t, 4);
      t += __shfl_xor(t, 8);
      lrun[rr] = lrun[rr] * alpha[rr] + t;
    }
    #pragma unroll
    for (int j = 0; j < 8; ++j)
      #pragma unroll
      for (int rr = 0; rr < 4; ++rr)
        o[j][rr] *= alpha[rr];

    #pragma unroll
    for (int ct = 0; ct < 4; ++ct)
      #pragma unroll
      for (int rr = 0; rr < 4; ++rr)
        p_lds[w * 16 + quad * 4 + rr][ct * 16 + lq] = f2bf(s[ct][rr]);

    bf16x8 pf[2];
    pf[0] = *(const bf16x8*)&p_lds[w * 16 + lq][quad * 8];
    pf[1] = *(const bf16x8*)&p_lds[w * 16 + lq][32 + quad * 8];

    const u16* vp = vT + (size_t)bh * 128 * 1024 + k0 + quad * 8;
    #pragma unroll
    for (int j = 0; j < 8; ++j) {
      #pragma unroll
      for (int ks2 = 0; ks2 < 2; ++ks2) {
        const bf16x8 vf = *(const bf16x8*)(vp + (size_t)(j * 16 + lq) * 1024 + ks2 * 32);
        o[j] = MFMA_BF16(pf[ks2], vf, o[j]);
      }
    }
  }

  const int h = bh & 15;
  #pragma unroll
  for (int rr = 0; rr < 4; ++rr) {
    const int row = l0 + w * 16 + quad * 4 + rr;
    const float inv = (row < ql) ? (1.0f / lrun[rr]) : 0.0f;
    u16* op = ao + ((size_t)b * 512 + row) * 2048 + h * 128 + lq;
    #pragma unroll
    for (int j = 0; j < 8; ++j)
      op[j * 16] = f2bf(o[j][rr] * inv);
  }
}

extern "C" void kernel_launch(void* const* d_in, const int* in_sizes, int n_in,
                              void* d_out, int out_size, void* d_ws, size_t ws_size,
                              hipStream_t stream) {
  (void)in_sizes; (void)n_in; (void)out_size; (void)ws_size;
  const float* x       = (const float*)d_in[0];
  const float* latents = (const float*)d_in[1];
  const float* t_emb   = (const float*)d_in[2];
  const int*   q_lens  = (const int*)d_in[3];
  const int*   k_lens  = (const int*)d_in[4];
  const float* ln_w    = (const float*)d_in[5];
  const float* ln_b    = (const float*)d_in[6];
  const float* ssg     = (const float*)d_in[7];
  const float* Wq      = (const float*)d_in[8];
  const float* bq      = (const float*)d_in[9];
  const float* Wkv     = (const float*)d_in[10];
  const float* bkv     = (const float*)d_in[11];
  const float* Wo      = (const float*)d_in[12];
  const float* bo      = (const float*)d_in[13];
  float* out = (float*)d_out;

  u16* ws = (u16*)d_ws;
  const size_t MEG = (size_t)1 << 20;      // elements
  u16* WqT  = ws;                 //  4M elems: (2048 x 2048) bf16, N-major
  u16* WoT  = ws + 4  * MEG;      //  4M
  u16* WkvT = ws + 8  * MEG;      //  8M: (4096 x 2048)
  u16* xk   = ws + 16 * MEG;      //  8M: (B*K, 2048)
  u16* lat  = ws + 24 * MEG;      //  4M: (B*L, 2048)
  u16* qb   = ws + 28 * MEG;      //  4M: (B,H,L,C)
  u16* kbuf = ws + 32 * MEG;      //  8M: (B,H,K,C)
  u16* vTb  = ws + 40 * MEG;      //  8M: (B,H,C,K)
  u16* aob  = ws + 48 * MEG;      //  4M: (B*L, 2048)

  ln_x_kernel<<<dim3(4096), dim3(256), 0, stream>>>(x, ln_w, ln_b, xk);
  ln_lat_kernel<<<dim3(2048), dim3(256), 0, stream>>>(latents, t_emb, ssg, lat);

  transpose_bf16_kernel<<<dim3(64, 64),  dim3(256), 0, stream>>>(Wq,  WqT,  2048, 2048);
  transpose_bf16_kernel<<<dim3(64, 64),  dim3(256), 0, stream>>>(Wo,  WoT,  2048, 2048);
  transpose_bf16_kernel<<<dim3(128, 64), dim3(256), 0, stream>>>(Wkv, WkvT, 2048, 4096);

  gemm_bf16_kernel<<<dim3(16, 16), dim3(256), 0, stream>>>(
      lat, WqT, 2048, 2048, 2048, 0, bq, qb, nullptr, nullptr, nullptr, nullptr, nullptr);
  gemm_bf16_kernel<<<dim3(32, 32), dim3(256), 0, stream>>>(
      xk, WkvT, 4096, 4096, 2048, 1, bkv, nullptr, kbuf, vTb, nullptr, nullptr, nullptr);

  attn_kernel<<<dim3(8, 64), dim3(256), 0, stream>>>(qb, kbuf, vTb, k_lens, q_lens, aob);

  gemm_bf16_kernel<<<dim3(16, 16), dim3(256), 0, stream>>>(
      aob, WoT, 2048, 2048, 2048, 2, bo, nullptr, nullptr, nullptr, out, t_emb, ssg);
}

// Round 3
// 473.649 us; speedup vs baseline: 1.0806x; 1.0215x over previous
//
#include <hip/hip_runtime.h>

typedef unsigned short u16;
typedef short bf16x8 __attribute__((ext_vector_type(8)));
typedef float f32x4 __attribute__((ext_vector_type(4)));

#define MFMA_BF16(a, b, c) __builtin_amdgcn_mfma_f32_16x16x32_bf16((a), (b), (c), 0, 0, 0)

__device__ __forceinline__ u16 f2bf(float f) {
  union { float f; unsigned int u; } cv;
  cv.f = f;
  unsigned int u = cv.u + 0x7fffu + ((cv.u >> 16) & 1u);
  return (u16)(u >> 16);
}

// ---------------- LayerNorm over x rows (2048 wide), write bf16 ----------------
__global__ __launch_bounds__(256) void ln_x_kernel(
    const float* __restrict__ x, const float* __restrict__ w,
    const float* __restrict__ b, u16* __restrict__ outp)
{
  const int row = blockIdx.x;
  const int tid = threadIdx.x;
  const float4* xr = (const float4*)(x + (size_t)row * 2048);
  float4 v0 = xr[tid];
  float4 v1 = xr[tid + 256];
  float sum = v0.x + v0.y + v0.z + v0.w + v1.x + v1.y + v1.z + v1.w;
  float sq  = v0.x*v0.x + v0.y*v0.y + v0.z*v0.z + v0.w*v0.w
            + v1.x*v1.x + v1.y*v1.y + v1.z*v1.z + v1.w*v1.w;
  #pragma unroll
  for (int off = 32; off > 0; off >>= 1) {
    sum += __shfl_xor(sum, off);
    sq  += __shfl_xor(sq, off);
  }
  __shared__ float red[8];
  if ((tid & 63) == 0) { red[tid >> 6] = sum; red[(tid >> 6) + 4] = sq; }
  __syncthreads();
  sum = red[0] + red[1] + red[2] + red[3];
  sq  = red[4] + red[5] + red[6] + red[7];
  const float mean = sum * (1.0f / 2048.0f);
  const float var  = sq * (1.0f / 2048.0f) - mean * mean;
  const float rstd = rsqrtf(var + 1e-5f);
  const float4* w4 = (const float4*)w;
  const float4* b4 = (const float4*)b;
  ushort4* orow = (ushort4*)(outp + (size_t)row * 2048);
  #pragma unroll
  for (int j = 0; j < 2; ++j) {
    const int idx = tid + j * 256;
    const float4 v = j ? v1 : v0;
    const float4 ww = w4[idx];
    const float4 bb = b4[idx];
    ushort4 o;
    o.x = f2bf((v.x - mean) * rstd * ww.x + bb.x);
    o.y = f2bf((v.y - mean) * rstd * ww.y + bb.y);
    o.z = f2bf((v.z - mean) * rstd * ww.z + bb.z);
    o.w = f2bf((v.w - mean) * rstd * ww.w + bb.w);
    orow[idx] = o;
  }
}

// ---------------- LayerNorm over latents + AdaLN modulation, write bf16 ----------------
__global__ __launch_bounds__(256) void ln_lat_kernel(
    const float* __restrict__ latents, const float* __restrict__ t_emb,
    const float* __restrict__ ssg, u16* __restrict__ outp)
{
  const int row  = blockIdx.x;     // b*512 + l
  const int bidx = row >> 9;
  const int tid  = threadIdx.x;
  const float4* xr = (const float4*)(latents + (size_t)row * 2048);
  float4 v0 = xr[tid];
  float4 v1 = xr[tid + 256];
  float sum = v0.x + v0.y + v0.z + v0.w + v1.x + v1.y + v1.z + v1.w;
  float sq  = v0.x*v0.x + v0.y*v0.y + v0.z*v0.z + v0.w*v0.w
            + v1.x*v1.x + v1.y*v1.y + v1.z*v1.z + v1.w*v1.w;
  #pragma unroll
  for (int off = 32; off > 0; off >>= 1) {
    sum += __shfl_xor(sum, off);
    sq  += __shfl_xor(sq, off);
  }
  __shared__ float red[8];
  if ((tid & 63) == 0) { red[tid >> 6] = sum; red[(tid >> 6) + 4] = sq; }
  __syncthreads();
  sum = red[0] + red[1] + red[2] + red[3];
  sq  = red[4] + red[5] + red[6] + red[7];
  const float mean = sum * (1.0f / 2048.0f);
  const float var  = sq * (1.0f / 2048.0f) - mean * mean;
  const float rstd = rsqrtf(var + 1e-5f);
  const float4* te = (const float4*)(t_emb + (size_t)bidx * 3 * 2048);
  const float4* sg = (const float4*)ssg;
  ushort4* orow = (ushort4*)(outp + (size_t)row * 2048);
  #pragma unroll
  for (int j = 0; j < 2; ++j) {
    const int idx = tid + j * 256;
    const float4 v = j ? v1 : v0;
    const float4 t0 = te[idx];        // shift row
    const float4 t1 = te[512 + idx];  // scale row
    const float4 s0 = sg[idx];
    const float4 s1 = sg[512 + idx];
    ushort4 o;
    o.x = f2bf(((v.x - mean) * rstd) * (1.0f + t1.x + s1.x) + (t0.x + s0.x));
    o.y = f2bf(((v.y - mean) * rstd) * (1.0f + t1.y + s1.y) + (t0.y + s0.y));
    o.z = f2bf(((v.z - mean) * rstd) * (1.0f + t1.z + s1.z) + (t0.z + s0.z));
    o.w = f2bf(((v.w - mean) * rstd) * (1.0f + t1.w + s1.w) + (t0.w + s0.w));
    orow[idx] = o;
  }
}

// ---------------- fp32 (R x C) -> bf16 transposed (C x R) ----------------
__global__ __launch_bounds__(256) void transpose_bf16_kernel(
    const float* __restrict__ in, u16* __restrict__ outp, int R, int C)
{
  __shared__ float tile[32][33];
  const int tx = threadIdx.x & 31;
  const int ty = threadIdx.x >> 5;   // 0..7
  const int c0 = blockIdx.x * 32;
  const int r0 = blockIdx.y * 32;
  #pragma unroll
  for (int i = 0; i < 4; ++i)
    tile[ty + i * 8][tx] = in[(size_t)(r0 + ty + i * 8) * C + c0 + tx];
  __syncthreads();
  #pragma unroll
  for (int i = 0; i < 4; ++i)
    outp[(size_t)(c0 + ty + i * 8) * R + r0 + tx] = f2bf(tile[tx][ty + i * 8]);
}

// ---------------- bf16 MFMA GEMM: BK=64, register staging pre-barrier ----------------
// C = A (MxK) * BT (NxK)^T + bias, fused epilogues:
// mode 0: q proj    -> out_q  bf16 (B,H,L,C)
// mode 1: kv proj   -> out_k  bf16 (B,H,K,C), out_vT bf16 (B,H,C,K)
// mode 2: out proj  -> out_f  fp32 (B*L, D), fused * gate
__global__ __launch_bounds__(256) void gemm_bf16_kernel(
    const u16* __restrict__ A, const u16* __restrict__ BT,
    int M, int N, int Kd, int mode,
    const float* __restrict__ bias,
    u16* __restrict__ out_q, u16* __restrict__ out_k, u16* __restrict__ out_vT,
    float* __restrict__ out_f,
    const float* __restrict__ t_emb, const float* __restrict__ ssg)
{
  // two k-halves, each with the proven round-1 padded layout (stride 40 elem = 80B)
  __shared__ u16 As[2][128][40];
  __shared__ u16 Bs[2][128][40];
  const int tid  = threadIdx.x;
  const int lane = tid & 63;
  const int wv   = tid >> 6;
  const int wm   = wv & 1, wn = wv >> 1;
  const int quad = lane >> 4, lq = lane & 15;
  const int m0 = blockIdx.y * 128, n0 = blockIdx.x * 128;

  f32x4 acc[4][4];
  #pragma unroll
  for (int i = 0; i < 4; ++i)
    #pragma unroll
    for (int j = 0; j < 4; ++j)
      acc[i][j] = (f32x4){0.f, 0.f, 0.f, 0.f};

  const int r  = tid >> 1;
  const int hf = (tid & 1) * 16;  // element offset within a 32-wide k half
  const u16* gA = A  + (size_t)(m0 + r) * Kd + hf;
  const u16* gB = BT + (size_t)(n0 + r) * Kd + hf;

  for (int k0 = 0; k0 < Kd; k0 += 64) {
    // 8 loads in flight BEFORE the barrier: latency overlaps barrier wait +
    // other waves' MFMAs (register loads need no vmcnt drain at s_barrier).
    const uint4 a00 = *(const uint4*)(gA + k0);
    const uint4 a01 = *(const uint4*)(gA + k0 + 8);
    const uint4 a10 = *(const uint4*)(gA + k0 + 32);
    const uint4 a11 = *(const uint4*)(gA + k0 + 40);
    const uint4 b00 = *(const uint4*)(gB + k0);
    const uint4 b01 = *(const uint4*)(gB + k0 + 8);
    const uint4 b10 = *(const uint4*)(gB + k0 + 32);
    const uint4 b11 = *(const uint4*)(gB + k0 + 40);
    __syncthreads();                 // prior iteration's LDS reads done
    *(uint4*)&As[0][r][hf]     = a00;
    *(uint4*)&As[0][r][hf + 8] = a01;
    *(uint4*)&As[1][r][hf]     = a10;
    *(uint4*)&As[1][r][hf + 8] = a11;
    *(uint4*)&Bs[0][r][hf]     = b00;
    *(uint4*)&Bs[0][r][hf + 8] = b01;
    *(uint4*)&Bs[1][r][hf]     = b10;
    *(uint4*)&Bs[1][r][hf + 8] = b11;
    __syncthreads();
    // 32 MFMAs per barrier crossing (2 k-halves x 16)
    #pragma unroll
    for (int kk = 0; kk < 2; ++kk) {
      bf16x8 av[4], bv[4];
      #pragma unroll
      for (int i = 0; i < 4; ++i)
        av[i] = *(const bf16x8*)&As[kk][wm * 64 + i * 16 + lq][quad * 8];
      #pragma unroll
      for (int j = 0; j < 4; ++j)
        bv[j] = *(const bf16x8*)&Bs[kk][wn * 64 + j * 16 + lq][quad * 8];
      #pragma unroll
      for (int i = 0; i < 4; ++i)
        #pragma unroll
        for (int j = 0; j < 4; ++j)
          acc[i][j] = MFMA_BF16(av[i], bv[j], acc[i][j]);
    }
  }

  // epilogue; C/D layout: col = lane&15, row = quad*4 + reg
  #pragma unroll
  for (int i = 0; i < 4; ++i) {
    const int mlb = m0 + wm * 64 + i * 16 + quad * 4;
    #pragma unroll
    for (int j = 0; j < 4; ++j) {
      const int n = n0 + wn * 64 + j * 16 + lq;
      const float bs = bias[n];
      if (mode == 0) {
        const int h = n >> 7, c = n & 127;
        #pragma unroll
        for (int rr = 0; rr < 4; ++rr) {
          const int m = mlb + rr;
          const int bb = m >> 9, l = m & 511;
          out_q[((size_t)(bb * 16 + h) * 512 + l) * 128 + c] = f2bf(acc[i][j][rr] + bs);
        }
      } else if (mode == 1) {
        if (n < 2048) {
          const int h = n >> 7, c = n & 127;
          #pragma unroll
          for (int rr = 0; rr < 4; ++rr) {
            const int m = mlb + rr;
            const int bb = m >> 10, kk = m & 1023;
            out_k[((size_t)(bb * 16 + h) * 1024 + kk) * 128 + c] = f2bf(acc[i][j][rr] + bs);
          }
        } else {
          const int n2 = n - 2048;
          const int h = n2 >> 7, c = n2 & 127;
          #pragma unroll
          for (int rr = 0; rr < 4; ++rr) {
            const int m = mlb + rr;
            const int bb = m >> 10, kk = m & 1023;
            out_vT[((size_t)(bb * 16 + h) * 128 + c) * 1024 + kk] = f2bf(acc[i][j][rr] + bs);
          }
        }
      } else {
        #pragma unroll
        for (int rr = 0; rr < 4; ++rr) {
          const int m = mlb + rr;
          const int bb = m >> 9;
          const float g = t_emb[((size_t)bb * 3 + 2) * 2048 + n] + ssg[2 * 2048 + n];
          out_f[(size_t)m * 2048 + n] = (acc[i][j][rr] + bs) * g;
        }
      }
    }
  }
}

// ---------------- flash attention: per (b,h, 64-row q tile) ----------------
#define ATT_SCALE 0.08838834764831845f  // 1/sqrt(128)

__global__ __launch_bounds__(256) void attn_kernel(
    const u16* __restrict__ qb, const u16* __restrict__ kb,
    const u16* __restrict__ vT, const int* __restrict__ k_lens,
    const int* __restrict__ q_lens, u16* __restrict__ ao)
{
  __shared__ u16 p_lds[64][72];   // row stride 144B (16B-aligned, 2-way banks)
  const int tid  = threadIdx.x;
  const int w    = tid >> 6;
  const int lane = tid & 63;
  const int quad = lane >> 4, lq = lane & 15;
  const int bh = blockIdx.y;           // b*16 + h
  const int b  = bh >> 4;
  const int l0 = blockIdx.x * 64;
  const int kl = k_lens[b];
  const int ql = q_lens[b];

  bf16x8 qf[4];
  {
    const u16* qp = qb + ((size_t)bh * 512 + l0 + w * 16 + lq) * 128 + quad * 8;
    #pragma unroll
    for (int ks = 0; ks < 4; ++ks)
      qf[ks] = *(const bf16x8*)(qp + ks * 32);
  }

  f32x4 o[8];
  #pragma unroll
  for (int j = 0; j < 8; ++j) o[j] = (f32x4){0.f, 0.f, 0.f, 0.f};
  float mrun[4], lrun[4];
  #pragma unroll
  for (int rr = 0; rr < 4; ++rr) { mrun[rr] = -__builtin_inff(); lrun[rr] = 0.f; }

  const int nkt = (kl + 63) >> 6;
  for (int kt = 0; kt < nkt; ++kt) {
    const int k0 = kt * 64;
    f32x4 s[4];
    const u16* kp = kb + ((size_t)bh * 1024 + k0) * 128 + quad * 8;
    #pragma unroll
    for (int ct = 0; ct < 4; ++ct) {
      s[ct] = (f32x4){0.f, 0.f, 0.f, 0.f};
      const u16* kpp = kp + (size_t)(ct * 16 + lq) * 128;
      #pragma unroll
      for (int ks = 0; ks < 4; ++ks) {
        const bf16x8 kf = *(const bf16x8*)(kpp + ks * 32);
        s[ct] = MFMA_BF16(qf[ks], kf, s[ct]);
      }
    }
    #pragma unroll
    for (int ct = 0; ct < 4; ++ct) {
      const bool valid = (k0 + ct * 16 + lq) < kl;
      #pragma unroll
      for (int rr = 0; rr < 4; ++rr) {
        const float sv = s[ct][rr] * ATT_SCALE;
        s[ct][rr] = valid ? sv : -__builtin_inff();
      }
    }
    float mnew[4], alpha[4], rs[4];
    #pragma unroll
    for (int rr = 0; rr < 4; ++rr) {
      float tm = fmaxf(fmaxf(s[0][rr], s[1][rr]), fmaxf(s[2][rr], s[3][rr]));
      tm = fmaxf(tm, __shfl_xor(tm, 1));
      tm = fmaxf(tm, __shfl_xor(tm, 2));
      tm = fmaxf(tm, __shfl_xor(tm, 4));
      tm = fmaxf(tm, __shfl_xor(tm, 8));
      const float mn = fmaxf(mrun[rr], tm);
      alpha[rr] = __expf(mrun[rr] - mn);
      mrun[rr] = mn;
      mnew[rr] = mn;
      rs[rr] = 0.f;
    }
    #pragma unroll
    for (int ct = 0; ct < 4; ++ct)
      #pragma unroll
      for (int rr = 0; rr < 4; ++rr) {
        const float p = __expf(s[ct][rr] - mnew[rr]);
        s[ct][rr] = p;
        rs[rr] += p;
      }
    #pragma unroll
    for (int rr = 0; rr < 4; ++rr) {
      float t = rs[rr];
      t += __shfl_xor(t, 1);
      t += __shfl_xor(t, 2);
      t += __shfl_xor(t, 4);
      t += __shfl_xor(t, 8);
      lrun[rr] = lrun[rr] * alpha[rr] + t;
    }
    #pragma unroll
    for (int j = 0; j < 8; ++j)
      #pragma unroll
      for (int rr = 0; rr < 4; ++rr)
        o[j][rr] *= alpha[rr];

    #pragma unroll
    for (int ct = 0; ct < 4; ++ct)
      #pragma unroll
      for (int rr = 0; rr < 4; ++rr)
        p_lds[w * 16 + quad * 4 + rr][ct * 16 + lq] = f2bf(s[ct][rr]);

    bf16x8 pf[2];
    pf[0] = *(const bf16x8*)&p_lds[w * 16 + lq][quad * 8];
    pf[1] = *(const bf16x8*)&p_lds[w * 16 + lq][32 + quad * 8];

    const u16* vp = vT + (size_t)bh * 128 * 1024 + k0 + quad * 8;
    #pragma unroll
    for (int j = 0; j < 8; ++j) {
      #pragma unroll
      for (int ks2 = 0; ks2 < 2; ++ks2) {
        const bf16x8 vf = *(const bf16x8*)(vp + (size_t)(j * 16 + lq) * 1024 + ks2 * 32);
        o[j] = MFMA_BF16(pf[ks2], vf, o[j]);
      }
    }
  }

  const int h = bh & 15;
  #pragma unroll
  for (int rr = 0; rr < 4; ++rr) {
    const int row = l0 + w * 16 + quad * 4 + rr;
    const float inv = (row < ql) ? (1.0f / lrun[rr]) : 0.0f;
    u16* op = ao + ((size_t)b * 512 + row) * 2048 + h * 128 + lq;
    #pragma unroll
    for (int j = 0; j < 8; ++j)
      op[j * 16] = f2bf(o[j][rr] * inv);
  }
}

extern "C" void kernel_launch(void* const* d_in, const int* in_sizes, int n_in,
                              void* d_out, int out_size, void* d_ws, size_t ws_size,
                              hipStream_t stream) {
  (void)in_sizes; (void)n_in; (void)out_size; (void)ws_size;
  const float* x       = (const float*)d_in[0];
  const float* latents = (const float*)d_in[1];
  const float* t_emb   = (const float*)d_in[2];
  const int*   q_lens  = (const int*)d_in[3];
  const int*   k_lens  = (const int*)d_in[4];
  const float* ln_w    = (const float*)d_in[5];
  const float* ln_b    = (const float*)d_in[6];
  const float* ssg     = (const float*)d_in[7];
  const float* Wq      = (const float*)d_in[8];
  const float* bq      = (const float*)d_in[9];
  const float* Wkv     = (const float*)d_in[10];
  const float* bkv     = (const float*)d_in[11];
  const float* Wo      = (const float*)d_in[12];
  const float* bo      = (const float*)d_in[13];
  float* out = (float*)d_out;

  u16* ws = (u16*)d_ws;
  const size_t MEG = (size_t)1 << 20;      // elements
  u16* WqT  = ws;                 //  4M elems: (2048 x 2048) bf16, N-major
  u16* WoT  = ws + 4  * MEG;      //  4M
  u16* WkvT = ws + 8  * MEG;      //  8M: (4096 x 2048)
  u16* xk   = ws + 16 * MEG;      //  8M: (B*K, 2048)
  u16* lat  = ws + 24 * MEG;      //  4M: (B*L, 2048)
  u16* qb   = ws + 28 * MEG;      //  4M: (B,H,L,C)
  u16* kbuf = ws + 32 * MEG;      //  8M: (B,H,K,C)
  u16* vTb  = ws + 40 * MEG;      //  8M: (B,H,C,K)
  u16* aob  = ws + 48 * MEG;      //  4M: (B*L, 2048)

  ln_x_kernel<<<dim3(4096), dim3(256), 0, stream>>>(x, ln_w, ln_b, xk);
  ln_lat_kernel<<<dim3(2048), dim3(256), 0, stream>>>(latents, t_emb, ssg, lat);

  transpose_bf16_kernel<<<dim3(64, 64),  dim3(256), 0, stream>>>(Wq,  WqT,  2048, 2048);
  transpose_bf16_kernel<<<dim3(64, 64),  dim3(256), 0, stream>>>(Wo,  WoT,  2048, 2048);
  transpose_bf16_kernel<<<dim3(128, 64), dim3(256), 0, stream>>>(Wkv, WkvT, 2048, 4096);

  gemm_bf16_kernel<<<dim3(16, 16), dim3(256), 0, stream>>>(
      lat, WqT, 2048, 2048, 2048, 0, bq, qb, nullptr, nullptr, nullptr, nullptr, nullptr);
  gemm_bf16_kernel<<<dim3(32, 32), dim3(256), 0, stream>>>(
      xk, WkvT, 4096, 4096, 2048, 1, bkv, nullptr, kbuf, vTb, nullptr, nullptr, nullptr);

  attn_kernel<<<dim3(8, 64), dim3(256), 0, stream>>>(qb, kbuf, vTb, k_lens, q_lens, aob);

  gemm_bf16_kernel<<<dim3(16, 16), dim3(256), 0, stream>>>(
      aob, WoT, 2048, 2048, 2048, 2, bo, nullptr, nullptr, nullptr, out, t_emb, ssg);
}

// Round 4
// 442.332 us; speedup vs baseline: 1.1571x; 1.0708x over previous
//
#include <hip/hip_runtime.h>

typedef unsigned short u16;
typedef short bf16x8 __attribute__((ext_vector_type(8)));
typedef float f32x4 __attribute__((ext_vector_type(4)));

#define MFMA_BF16(a, b, c) __builtin_amdgcn_mfma_f32_16x16x32_bf16((a), (b), (c), 0, 0, 0)

__device__ __forceinline__ u16 f2bf(float f) {
  union { float f; unsigned int u; } cv;
  cv.f = f;
  unsigned int u = cv.u + 0x7fffu + ((cv.u >> 16) & 1u);
  return (u16)(u >> 16);
}

// ---------------- fused LayerNorm: rows 0..4095 = x-LN, 4096..6143 = latent-AdaLN ----------------
__global__ __launch_bounds__(256) void ln_fused_kernel(
    const float* __restrict__ x, const float* __restrict__ w,
    const float* __restrict__ b, const float* __restrict__ latents,
    const float* __restrict__ t_emb, const float* __restrict__ ssg,
    u16* __restrict__ xk_out, u16* __restrict__ lat_out)
{
  const int blk = blockIdx.x;
  const bool is_x = blk < 4096;
  const int row = is_x ? blk : blk - 4096;
  const int tid = threadIdx.x;
  const float* src = is_x ? (x + (size_t)row * 2048) : (latents + (size_t)row * 2048);
  const float4* xr = (const float4*)src;
  float4 v0 = xr[tid];
  float4 v1 = xr[tid + 256];
  float sum = v0.x + v0.y + v0.z + v0.w + v1.x + v1.y + v1.z + v1.w;
  float sq  = v0.x*v0.x + v0.y*v0.y + v0.z*v0.z + v0.w*v0.w
            + v1.x*v1.x + v1.y*v1.y + v1.z*v1.z + v1.w*v1.w;
  #pragma unroll
  for (int off = 32; off > 0; off >>= 1) {
    sum += __shfl_xor(sum, off);
    sq  += __shfl_xor(sq, off);
  }
  __shared__ float red[8];
  if ((tid & 63) == 0) { red[tid >> 6] = sum; red[(tid >> 6) + 4] = sq; }
  __syncthreads();
  sum = red[0] + red[1] + red[2] + red[3];
  sq  = red[4] + red[5] + red[6] + red[7];
  const float mean = sum * (1.0f / 2048.0f);
  const float var  = sq * (1.0f / 2048.0f) - mean * mean;
  const float rstd = rsqrtf(var + 1e-5f);
  if (is_x) {
    const float4* w4 = (const float4*)w;
    const float4* b4 = (const float4*)b;
    ushort4* orow = (ushort4*)(xk_out + (size_t)row * 2048);
    #pragma unroll
    for (int j = 0; j < 2; ++j) {
      const int idx = tid + j * 256;
      const float4 v = j ? v1 : v0;
      const float4 ww = w4[idx];
      const float4 bb = b4[idx];
      ushort4 o;
      o.x = f2bf((v.x - mean) * rstd * ww.x + bb.x);
      o.y = f2bf((v.y - mean) * rstd * ww.y + bb.y);
      o.z = f2bf((v.z - mean) * rstd * ww.z + bb.z);
      o.w = f2bf((v.w - mean) * rstd * ww.w + bb.w);
      orow[idx] = o;
    }
  } else {
    const int bidx = row >> 9;
    const float4* te = (const float4*)(t_emb + (size_t)bidx * 3 * 2048);
    const float4* sg = (const float4*)ssg;
    ushort4* orow = (ushort4*)(lat_out + (size_t)row * 2048);
    #pragma unroll
    for (int j = 0; j < 2; ++j) {
      const int idx = tid + j * 256;
      const float4 v = j ? v1 : v0;
      const float4 t0 = te[idx];        // shift row
      const float4 t1 = te[512 + idx];  // scale row
      const float4 s0 = sg[idx];
      const float4 s1 = sg[512 + idx];
      ushort4 o;
      o.x = f2bf(((v.x - mean) * rstd) * (1.0f + t1.x + s1.x) + (t0.x + s0.x));
      o.y = f2bf(((v.y - mean) * rstd) * (1.0f + t1.y + s1.y) + (t0.y + s0.y));
      o.z = f2bf(((v.z - mean) * rstd) * (1.0f + t1.z + s1.z) + (t0.z + s0.z));
      o.w = f2bf(((v.w - mean) * rstd) * (1.0f + t1.w + s1.w) + (t0.w + s0.w));
      orow[idx] = o;
    }
  }
}

// ---------------- fused transposes: Wq, Wo, Wkv  fp32 (RxC) -> bf16 (CxR) ----------------
__global__ __launch_bounds__(256) void transpose_all_kernel(
    const float* __restrict__ Wq, const float* __restrict__ Wo,
    const float* __restrict__ Wkv,
    u16* __restrict__ WqT, u16* __restrict__ WoT, u16* __restrict__ WkvT)
{
  __shared__ float tile[32][33];
  int t = blockIdx.x;
  const float* in;
  u16* outp;
  int C, cx, ry;
  if (t < 4096)       { in = Wq;  outp = WqT;  C = 2048; cx = t & 63;  ry = t >> 6; }
  else if (t < 8192)  { t -= 4096; in = Wo;  outp = WoT;  C = 2048; cx = t & 63;  ry = t >> 6; }
  else                { t -= 8192; in = Wkv; outp = WkvT; C = 4096; cx = t & 127; ry = t >> 7; }
  const int R = 2048;
  const int c0 = cx * 32;
  const int r0 = ry * 32;
  const int tx = threadIdx.x & 31;
  const int ty = threadIdx.x >> 5;   // 0..7
  #pragma unroll
  for (int i = 0; i < 4; ++i)
    tile[ty + i * 8][tx] = in[(size_t)(r0 + ty + i * 8) * C + c0 + tx];
  __syncthreads();
  #pragma unroll
  for (int i = 0; i < 4; ++i)
    outp[(size_t)(c0 + ty + i * 8) * R + r0 + tx] = f2bf(tile[tx][ty + i * 8]);
}

// ---------------- bf16 MFMA GEMM: BK=64, register staging pre-barrier ----------------
// BM = 128 (waves 2x2, acc 4x4) or 64 (waves 2x2, acc 2x4). BN = 128 always.
// C = A (MxK) * BT (NxK)^T + bias, fused epilogues:
// mode 0: q proj    -> out_q  bf16 (B,H,L,C)
// mode 1: kv proj   -> out_k  bf16 (B,H,K,C), out_vT bf16 (B,H,C,K)
// mode 2: out proj  -> out_f  fp32 (B*L, D), fused * gate
template<int BM>
__global__ __launch_bounds__(256) void gemm_bf16_kernel(
    const u16* __restrict__ A, const u16* __restrict__ BT,
    int M, int N, int Kd, int mode,
    const float* __restrict__ bias,
    u16* __restrict__ out_q, u16* __restrict__ out_k, u16* __restrict__ out_vT,
    float* __restrict__ out_f,
    const float* __restrict__ t_emb, const float* __restrict__ ssg)
{
  constexpr int TI = BM / 32;        // wave covers BM/2 rows = TI 16-row tiles
  __shared__ u16 As[2][BM][40];      // padded: stride 40 elem = 80B
  __shared__ u16 Bs[2][128][40];
  const int tid  = threadIdx.x;
  const int lane = tid & 63;
  const int wv   = tid >> 6;
  const int wm   = wv & 1, wn = wv >> 1;
  const int quad = lane >> 4, lq = lane & 15;
  const int m0 = blockIdx.y * BM, n0 = blockIdx.x * 128;

  f32x4 acc[TI][4];
  #pragma unroll
  for (int i = 0; i < TI; ++i)
    #pragma unroll
    for (int j = 0; j < 4; ++j)
      acc[i][j] = (f32x4){0.f, 0.f, 0.f, 0.f};

  // B staging map (both BM): row rB = tid>>1, 32B chunk hfB=(tid&1)*16, both k-halves
  const int rB  = tid >> 1;
  const int hfB = (tid & 1) * 16;
  const u16* gB = BT + (size_t)(n0 + rB) * Kd + hfB;
  // A staging map:
  //  BM=128: row tid>>1, chunk (tid&1)*16, both halves (4 uint4)
  //  BM=64 : row tid>>2, half (tid>>1)&1, chunk (tid&1)*16 (2 uint4)
  const int rA  = (BM == 128) ? (tid >> 1) : (tid >> 2);
  const int hA  = (BM == 128) ? 0 : ((tid >> 1) & 1);
  const int hfA = (tid & 1) * 16;
  const u16* gA = A + (size_t)(m0 + rA) * Kd + hA * 32 + hfA;

  for (int k0 = 0; k0 < Kd; k0 += 64) {
    // loads in flight BEFORE the barrier: latency overlaps barrier wait +
    // other waves' MFMAs (register loads need no vmcnt drain at s_barrier).
    uint4 a00, a01, a10, a11;
    a00 = *(const uint4*)(gA + k0);
    a01 = *(const uint4*)(gA + k0 + 8);
    if (BM == 128) {
      a10 = *(const uint4*)(gA + k0 + 32);
      a11 = *(const uint4*)(gA + k0 + 40);
    }
    const uint4 b00 = *(const uint4*)(gB + k0);
    const uint4 b01 = *(const uint4*)(gB + k0 + 8);
    const uint4 b10 = *(const uint4*)(gB + k0 + 32);
    const uint4 b11 = *(const uint4*)(gB + k0 + 40);
    __syncthreads();                 // prior iteration's LDS reads done
    *(uint4*)&As[hA][rA][hfA]     = a00;
    *(uint4*)&As[hA][rA][hfA + 8] = a01;
    if (BM == 128) {
      *(uint4*)&As[1][rA][hfA]     = a10;
      *(uint4*)&As[1][rA][hfA + 8] = a11;
    }
    *(uint4*)&Bs[0][rB][hfB]     = b00;
    *(uint4*)&Bs[0][rB][hfB + 8] = b01;
    *(uint4*)&Bs[1][rB][hfB]     = b10;
    *(uint4*)&Bs[1][rB][hfB + 8] = b11;
    __syncthreads();
    #pragma unroll
    for (int kk = 0; kk < 2; ++kk) {
      bf16x8 av[TI], bv[4];
      #pragma unroll
      for (int i = 0; i < TI; ++i)
        av[i] = *(const bf16x8*)&As[kk][wm * (BM / 2) + i * 16 + lq][quad * 8];
      #pragma unroll
      for (int j = 0; j < 4; ++j)
        bv[j] = *(const bf16x8*)&Bs[kk][wn * 64 + j * 16 + lq][quad * 8];
      #pragma unroll
      for (int i = 0; i < TI; ++i)
        #pragma unroll
        for (int j = 0; j < 4; ++j)
          acc[i][j] = MFMA_BF16(av[i], bv[j], acc[i][j]);
    }
  }

  // epilogue; C/D layout: col = lane&15, row = quad*4 + reg
  #pragma unroll
  for (int i = 0; i < TI; ++i) {
    const int mlb = m0 + wm * (BM / 2) + i * 16 + quad * 4;
    #pragma unroll
    for (int j = 0; j < 4; ++j) {
      const int n = n0 + wn * 64 + j * 16 + lq;
      const float bs = bias[n];
      if (mode == 0) {
        const int h = n >> 7, c = n & 127;
        #pragma unroll
        for (int rr = 0; rr < 4; ++rr) {
          const int m = mlb + rr;
          const int bb = m >> 9, l = m & 511;
          out_q[((size_t)(bb * 16 + h) * 512 + l) * 128 + c] = f2bf(acc[i][j][rr] + bs);
        }
      } else if (mode == 1) {
        if (n < 2048) {
          const int h = n >> 7, c = n & 127;
          #pragma unroll
          for (int rr = 0; rr < 4; ++rr) {
            const int m = mlb + rr;
            const int bb = m >> 10, kk = m & 1023;
            out_k[((size_t)(bb * 16 + h) * 1024 + kk) * 128 + c] = f2bf(acc[i][j][rr] + bs);
          }
        } else {
          const int n2 = n - 2048;
          const int h = n2 >> 7, c = n2 & 127;
          #pragma unroll
          for (int rr = 0; rr < 4; ++rr) {
            const int m = mlb + rr;
            const int bb = m >> 10, kk = m & 1023;
            out_vT[((size_t)(bb * 16 + h) * 128 + c) * 1024 + kk] = f2bf(acc[i][j][rr] + bs);
          }
        }
      } else {
        #pragma unroll
        for (int rr = 0; rr < 4; ++rr) {
          const int m = mlb + rr;
          const int bb = m >> 9;
          const float g = t_emb[((size_t)bb * 3 + 2) * 2048 + n] + ssg[2 * 2048 + n];
          out_f[(size_t)m * 2048 + n] = (acc[i][j][rr] + bs) * g;
        }
      }
    }
  }
}

// ---------------- flash attention: per (b,h, 64-row q tile) ----------------
#define ATT_SCALE 0.08838834764831845f  // 1/sqrt(128)

__global__ __launch_bounds__(256) void attn_kernel(
    const u16* __restrict__ qb, const u16* __restrict__ kb,
    const u16* __restrict__ vT, const int* __restrict__ k_lens,
    const int* __restrict__ q_lens, u16* __restrict__ ao)
{
  __shared__ u16 p_lds[64][72];   // row stride 144B (16B-aligned, 2-way banks)
  const int tid  = threadIdx.x;
  const int w    = tid >> 6;
  const int lane = tid & 63;
  const int quad = lane >> 4, lq = lane & 15;
  const int bh = blockIdx.y;           // b*16 + h
  const int b  = bh >> 4;
  const int l0 = blockIdx.x * 64;
  const int kl = k_lens[b];
  const int ql = q_lens[b];

  bf16x8 qf[4];
  {
    const u16* qp = qb + ((size_t)bh * 512 + l0 + w * 16 + lq) * 128 + quad * 8;
    #pragma unroll
    for (int ks = 0; ks < 4; ++ks)
      qf[ks] = *(const bf16x8*)(qp + ks * 32);
  }

  f32x4 o[8];
  #pragma unroll
  for (int j = 0; j < 8; ++j) o[j] = (f32x4){0.f, 0.f, 0.f, 0.f};
  float mrun[4], lrun[4];
  #pragma unroll
  for (int rr = 0; rr < 4; ++rr) { mrun[rr] = -__builtin_inff(); lrun[rr] = 0.f; }

  const int nkt = (kl + 63) >> 6;
  for (int kt = 0; kt < nkt; ++kt) {
    const int k0 = kt * 64;
    f32x4 s[4];
    const u16* kp = kb + ((size_t)bh * 1024 + k0) * 128 + quad * 8;
    #pragma unroll
    for (int ct = 0; ct < 4; ++ct) {
      s[ct] = (f32x4){0.f, 0.f, 0.f, 0.f};
      const u16* kpp = kp + (size_t)(ct * 16 + lq) * 128;
      #pragma unroll
      for (int ks = 0; ks < 4; ++ks) {
        const bf16x8 kf = *(const bf16x8*)(kpp + ks * 32);
        s[ct] = MFMA_BF16(qf[ks], kf, s[ct]);
      }
    }
    #pragma unroll
    for (int ct = 0; ct < 4; ++ct) {
      const bool valid = (k0 + ct * 16 + lq) < kl;
      #pragma unroll
      for (int rr = 0; rr < 4; ++rr) {
        const float sv = s[ct][rr] * ATT_SCALE;
        s[ct][rr] = valid ? sv : -__builtin_inff();
      }
    }
    float mnew[4], alpha[4], rs[4];
    #pragma unroll
    for (int rr = 0; rr < 4; ++rr) {
      float tm = fmaxf(fmaxf(s[0][rr], s[1][rr]), fmaxf(s[2][rr], s[3][rr]));
      tm = fmaxf(tm, __shfl_xor(tm, 1));
      tm = fmaxf(tm, __shfl_xor(tm, 2));
      tm = fmaxf(tm, __shfl_xor(tm, 4));
      tm = fmaxf(tm, __shfl_xor(tm, 8));
      const float mn = fmaxf(mrun[rr], tm);
      alpha[rr] = __expf(mrun[rr] - mn);
      mrun[rr] = mn;
      mnew[rr] = mn;
      rs[rr] = 0.f;
    }
    #pragma unroll
    for (int ct = 0; ct < 4; ++ct)
      #pragma unroll
      for (int rr = 0; rr < 4; ++rr) {
        const float p = __expf(s[ct][rr] - mnew[rr]);
        s[ct][rr] = p;
        rs[rr] += p;
      }
    #pragma unroll
    for (int rr = 0; rr < 4; ++rr) {
      float t = rs[rr];
      t += __shfl_xor(t, 1);
      t += __shfl_xor(t, 2);
      t += __shfl_xor(t, 4);
      t += __shfl_xor(t, 8);
      lrun[rr] = lrun[rr] * alpha[rr] + t;
    }
    #pragma unroll
    for (int j = 0; j < 8; ++j)
      #pragma unroll
      for (int rr = 0; rr < 4; ++rr)
        o[j][rr] *= alpha[rr];

    #pragma unroll
    for (int ct = 0; ct < 4; ++ct)
      #pragma unroll
      for (int rr = 0; rr < 4; ++rr)
        p_lds[w * 16 + quad * 4 + rr][ct * 16 + lq] = f2bf(s[ct][rr]);

    bf16x8 pf[2];
    pf[0] = *(const bf16x8*)&p_lds[w * 16 + lq][quad * 8];
    pf[1] = *(const bf16x8*)&p_lds[w * 16 + lq][32 + quad * 8];

    const u16* vp = vT + (size_t)bh * 128 * 1024 + k0 + quad * 8;
    #pragma unroll
    for (int j = 0; j < 8; ++j) {
      #pragma unroll
      for (int ks2 = 0; ks2 < 2; ++ks2) {
        const bf16x8 vf = *(const bf16x8*)(vp + (size_t)(j * 16 + lq) * 1024 + ks2 * 32);
        o[j] = MFMA_BF16(pf[ks2], vf, o[j]);
      }
    }
  }

  const int h = bh & 15;
  #pragma unroll
  for (int rr = 0; rr < 4; ++rr) {
    const int row = l0 + w * 16 + quad * 4 + rr;
    const float inv = (row < ql) ? (1.0f / lrun[rr]) : 0.0f;
    u16* op = ao + ((size_t)b * 512 + row) * 2048 + h * 128 + lq;
    #pragma unroll
    for (int j = 0; j < 8; ++j)
      op[j * 16] = f2bf(o[j][rr] * inv);
  }
}

extern "C" void kernel_launch(void* const* d_in, const int* in_sizes, int n_in,
                              void* d_out, int out_size, void* d_ws, size_t ws_size,
                              hipStream_t stream) {
  (void)in_sizes; (void)n_in; (void)out_size; (void)ws_size;
  const float* x       = (const float*)d_in[0];
  const float* latents = (const float*)d_in[1];
  const float* t_emb   = (const float*)d_in[2];
  const int*   q_lens  = (const int*)d_in[3];
  const int*   k_lens  = (const int*)d_in[4];
  const float* ln_w    = (const float*)d_in[5];
  const float* ln_b    = (const float*)d_in[6];
  const float* ssg     = (const float*)d_in[7];
  const float* Wq      = (const float*)d_in[8];
  const float* bq      = (const float*)d_in[9];
  const float* Wkv     = (const float*)d_in[10];
  const float* bkv     = (const float*)d_in[11];
  const float* Wo      = (const float*)d_in[12];
  const float* bo      = (const float*)d_in[13];
  float* out = (float*)d_out;

  u16* ws = (u16*)d_ws;
  const size_t MEG = (size_t)1 << 20;      // elements
  u16* WqT  = ws;                 //  4M elems: (2048 x 2048) bf16, N-major
  u16* WoT  = ws + 4  * MEG;      //  4M
  u16* WkvT = ws + 8  * MEG;      //  8M: (4096 x 2048)
  u16* xk   = ws + 16 * MEG;      //  8M: (B*K, 2048)
  u16* lat  = ws + 24 * MEG;      //  4M: (B*L, 2048)
  u16* qb   = ws + 28 * MEG;      //  4M: (B,H,L,C)
  u16* kbuf = ws + 32 * MEG;      //  8M: (B,H,K,C)
  u16* vTb  = ws + 40 * MEG;      //  8M: (B,H,C,K)
  u16* aob  = ws + 48 * MEG;      //  4M: (B*L, 2048)

  ln_fused_kernel<<<dim3(6144), dim3(256), 0, stream>>>(
      x, ln_w, ln_b, latents, t_emb, ssg, xk, lat);

  transpose_all_kernel<<<dim3(16384), dim3(256), 0, stream>>>(
      Wq, Wo, Wkv, WqT, WoT, WkvT);

  // q = lat @ Wq + bq  -> (B,H,L,C)   [BM=64: 512 blocks, 2/CU]
  gemm_bf16_kernel<64><<<dim3(16, 32), dim3(256), 0, stream>>>(
      lat, WqT, 2048, 2048, 2048, 0, bq, qb, nullptr, nullptr, nullptr, nullptr, nullptr);
  // kv = xk @ Wkv + bkv -> k (B,H,K,C), v^T (B,H,C,K)   [BM=128 control]
  gemm_bf16_kernel<128><<<dim3(32, 32), dim3(256), 0, stream>>>(
      xk, WkvT, 4096, 4096, 2048, 1, bkv, nullptr, kbuf, vTb, nullptr, nullptr, nullptr);

  attn_kernel<<<dim3(8, 64), dim3(256), 0, stream>>>(qb, kbuf, vTb, k_lens, q_lens, aob);

  // out = (attn_out @ Wo + bo) * gate   [BM=64]
  gemm_bf16_kernel<64><<<dim3(16, 32), dim3(256), 0, stream>>>(
      aob, WoT, 2048, 2048, 2048, 2, bo, nullptr, nullptr, nullptr, out, t_emb, ssg);
}

// Round 5
// 432.011 us; speedup vs baseline: 1.1847x; 1.0239x over previous
//
#include <hip/hip_runtime.h>

typedef unsigned short u16;
typedef short bf16x8 __attribute__((ext_vector_type(8)));
typedef float f32x4 __attribute__((ext_vector_type(4)));

#define MFMA_BF16(a, b, c) __builtin_amdgcn_mfma_f32_16x16x32_bf16((a), (b), (c), 0, 0, 0)
#define ATT_SCALE 0.08838834764831845f  // 1/sqrt(128)

__device__ __forceinline__ u16 f2bf(float f) {
  union { float f; unsigned int u; } cv;
  cv.f = f;
  unsigned int u = cv.u + 0x7fffu + ((cv.u >> 16) & 1u);
  return (u16)(u >> 16);
}

// ---------------- fused LayerNorm: rows 0..4095 = x-LN, 4096..6143 = latent-AdaLN ----------------
__global__ __launch_bounds__(256) void ln_fused_kernel(
    const float* __restrict__ x, const float* __restrict__ w,
    const float* __restrict__ b, const float* __restrict__ latents,
    const float* __restrict__ t_emb, const float* __restrict__ ssg,
    u16* __restrict__ xk_out, u16* __restrict__ lat_out)
{
  const int blk = blockIdx.x;
  const bool is_x = blk < 4096;
  const int row = is_x ? blk : blk - 4096;
  const int tid = threadIdx.x;
  const float* src = is_x ? (x + (size_t)row * 2048) : (latents + (size_t)row * 2048);
  const float4* xr = (const float4*)src;
  float4 v0 = xr[tid];
  float4 v1 = xr[tid + 256];
  float sum = v0.x + v0.y + v0.z + v0.w + v1.x + v1.y + v1.z + v1.w;
  float sq  = v0.x*v0.x + v0.y*v0.y + v0.z*v0.z + v0.w*v0.w
            + v1.x*v1.x + v1.y*v1.y + v1.z*v1.z + v1.w*v1.w;
  #pragma unroll
  for (int off = 32; off > 0; off >>= 1) {
    sum += __shfl_xor(sum, off);
    sq  += __shfl_xor(sq, off);
  }
  __shared__ float red[8];
  if ((tid & 63) == 0) { red[tid >> 6] = sum; red[(tid >> 6) + 4] = sq; }
  __syncthreads();
  sum = red[0] + red[1] + red[2] + red[3];
  sq  = red[4] + red[5] + red[6] + red[7];
  const float mean = sum * (1.0f / 2048.0f);
  const float var  = sq * (1.0f / 2048.0f) - mean * mean;
  const float rstd = rsqrtf(var + 1e-5f);
  if (is_x) {
    const float4* w4 = (const float4*)w;
    const float4* b4 = (const float4*)b;
    ushort4* orow = (ushort4*)(xk_out + (size_t)row * 2048);
    #pragma unroll
    for (int j = 0; j < 2; ++j) {
      const int idx = tid + j * 256;
      const float4 v = j ? v1 : v0;
      const float4 ww = w4[idx];
      const float4 bb = b4[idx];
      ushort4 o;
      o.x = f2bf((v.x - mean) * rstd * ww.x + bb.x);
      o.y = f2bf((v.y - mean) * rstd * ww.y + bb.y);
      o.z = f2bf((v.z - mean) * rstd * ww.z + bb.z);
      o.w = f2bf((v.w - mean) * rstd * ww.w + bb.w);
      orow[idx] = o;
    }
  } else {
    const int bidx = row >> 9;
    const float4* te = (const float4*)(t_emb + (size_t)bidx * 3 * 2048);
    const float4* sg = (const float4*)ssg;
    ushort4* orow = (ushort4*)(lat_out + (size_t)row * 2048);
    #pragma unroll
    for (int j = 0; j < 2; ++j) {
      const int idx = tid + j * 256;
      const float4 v = j ? v1 : v0;
      const float4 t0 = te[idx];        // shift row
      const float4 t1 = te[512 + idx];  // scale row
      const float4 s0 = sg[idx];
      const float4 s1 = sg[512 + idx];
      ushort4 o;
      o.x = f2bf(((v.x - mean) * rstd) * (1.0f + t1.x + s1.x) + (t0.x + s0.x));
      o.y = f2bf(((v.y - mean) * rstd) * (1.0f + t1.y + s1.y) + (t0.y + s0.y));
      o.z = f2bf(((v.z - mean) * rstd) * (1.0f + t1.z + s1.z) + (t0.z + s0.z));
      o.w = f2bf(((v.w - mean) * rstd) * (1.0f + t1.w + s1.w) + (t0.w + s0.w));
      orow[idx] = o;
    }
  }
}

// ---------------- fused transposes: Wq, Wo, Wkv  fp32 (RxC) -> bf16 (CxR) ----------------
__global__ __launch_bounds__(256) void transpose_all_kernel(
    const float* __restrict__ Wq, const float* __restrict__ Wo,
    const float* __restrict__ Wkv,
    u16* __restrict__ WqT, u16* __restrict__ WoT, u16* __restrict__ WkvT)
{
  __shared__ float tile[32][33];
  int t = blockIdx.x;
  const float* in;
  u16* outp;
  int C, cx, ry;
  if (t < 4096)       { in = Wq;  outp = WqT;  C = 2048; cx = t & 63;  ry = t >> 6; }
  else if (t < 8192)  { t -= 4096; in = Wo;  outp = WoT;  C = 2048; cx = t & 63;  ry = t >> 6; }
  else                { t -= 8192; in = Wkv; outp = WkvT; C = 4096; cx = t & 127; ry = t >> 7; }
  const int R = 2048;
  const int c0 = cx * 32;
  const int r0 = ry * 32;
  const int tx = threadIdx.x & 31;
  const int ty = threadIdx.x >> 5;   // 0..7
  #pragma unroll
  for (int i = 0; i < 4; ++i)
    tile[ty + i * 8][tx] = in[(size_t)(r0 + ty + i * 8) * C + c0 + tx];
  __syncthreads();
  #pragma unroll
  for (int i = 0; i < 4; ++i)
    outp[(size_t)(c0 + ty + i * 8) * R + r0 + tx] = f2bf(tile[tx][ty + i * 8]);
}

// ---------------- bf16 MFMA GEMM: BK=64, register staging pre-barrier ----------------
// MODE 0: q proj  -> out_q bf16 (B,H,L,C), fused * ATT_SCALE
// MODE 1: kv proj -> out_k bf16 (B,H,K,C), out_vT bf16 (B,H,C,K)
// MODE 2: out proj-> out_f fp32 (B*L, D), fused * gate
template<int BM, int MODE>
__global__ __launch_bounds__(256) void gemm_bf16_kernel(
    const u16* __restrict__ A, const u16* __restrict__ BT,
    int Kd,
    const float* __restrict__ bias,
    u16* __restrict__ out_q, u16* __restrict__ out_k, u16* __restrict__ out_vT,
    float* __restrict__ out_f,
    const float* __restrict__ t_emb, const float* __restrict__ ssg)
{
  constexpr int TI = BM / 32;        // wave covers BM/2 rows = TI 16-row tiles
  __shared__ u16 As[2][BM][40];      // padded: stride 40 elem = 80B
  __shared__ u16 Bs[2][128][40];
  const int tid  = threadIdx.x;
  const int lane = tid & 63;
  const int wv   = tid >> 6;
  const int wm   = wv & 1, wn = wv >> 1;
  const int quad = lane >> 4, lq = lane & 15;
  const int m0 = blockIdx.y * BM, n0 = blockIdx.x * 128;

  f32x4 acc[TI][4];
  #pragma unroll
  for (int i = 0; i < TI; ++i)
    #pragma unroll
    for (int j = 0; j < 4; ++j)
      acc[i][j] = (f32x4){0.f, 0.f, 0.f, 0.f};

  const int rB  = tid >> 1;
  const int hfB = (tid & 1) * 16;
  const u16* gB = BT + (size_t)(n0 + rB) * Kd + hfB;
  const int rA  = (BM == 128) ? (tid >> 1) : (tid >> 2);
  const int hA  = (BM == 128) ? 0 : ((tid >> 1) & 1);
  const int hfA = (tid & 1) * 16;
  const u16* gA = A + (size_t)(m0 + rA) * Kd + hA * 32 + hfA;

  for (int k0 = 0; k0 < Kd; k0 += 64) {
    uint4 a00, a01, a10, a11;
    a00 = *(const uint4*)(gA + k0);
    a01 = *(const uint4*)(gA + k0 + 8);
    if (BM == 128) {
      a10 = *(const uint4*)(gA + k0 + 32);
      a11 = *(const uint4*)(gA + k0 + 40);
    }
    const uint4 b00 = *(const uint4*)(gB + k0);
    const uint4 b01 = *(const uint4*)(gB + k0 + 8);
    const uint4 b10 = *(const uint4*)(gB + k0 + 32);
    const uint4 b11 = *(const uint4*)(gB + k0 + 40);
    __syncthreads();                 // prior iteration's LDS reads done
    *(uint4*)&As[hA][rA][hfA]     = a00;
    *(uint4*)&As[hA][rA][hfA + 8] = a01;
    if (BM == 128) {
      *(uint4*)&As[1][rA][hfA]     = a10;
      *(uint4*)&As[1][rA][hfA + 8] = a11;
    }
    *(uint4*)&Bs[0][rB][hfB]     = b00;
    *(uint4*)&Bs[0][rB][hfB + 8] = b01;
    *(uint4*)&Bs[1][rB][hfB]     = b10;
    *(uint4*)&Bs[1][rB][hfB + 8] = b11;
    __syncthreads();
    #pragma unroll
    for (int kk = 0; kk < 2; ++kk) {
      bf16x8 av[TI], bv[4];
      #pragma unroll
      for (int i = 0; i < TI; ++i)
        av[i] = *(const bf16x8*)&As[kk][wm * (BM / 2) + i * 16 + lq][quad * 8];
      #pragma unroll
      for (int j = 0; j < 4; ++j)
        bv[j] = *(const bf16x8*)&Bs[kk][wn * 64 + j * 16 + lq][quad * 8];
      #pragma unroll
      for (int i = 0; i < TI; ++i)
        #pragma unroll
        for (int j = 0; j < 4; ++j)
          acc[i][j] = MFMA_BF16(av[i], bv[j], acc[i][j]);
    }
  }

  // epilogue; C/D layout: col = lane&15, row = quad*4 + reg
  #pragma unroll
  for (int i = 0; i < TI; ++i) {
    const int mlb = m0 + wm * (BM / 2) + i * 16 + quad * 4;
    #pragma unroll
    for (int j = 0; j < 4; ++j) {
      const int n = n0 + wn * 64 + j * 16 + lq;
      const float bs = bias[n];
      if (MODE == 0) {
        const int h = n >> 7, c = n & 127;
        #pragma unroll
        for (int rr = 0; rr < 4; ++rr) {
          const int m = mlb + rr;
          const int bb = m >> 9, l = m & 511;
          out_q[((size_t)(bb * 16 + h) * 512 + l) * 128 + c] =
              f2bf((acc[i][j][rr] + bs) * ATT_SCALE);
        }
      } else if (MODE == 1) {
        if (n < 2048) {
          const int h = n >> 7, c = n & 127;
          #pragma unroll
          for (int rr = 0; rr < 4; ++rr) {
            const int m = mlb + rr;
            const int bb = m >> 10, kk = m & 1023;
            out_k[((size_t)(bb * 16 + h) * 1024 + kk) * 128 + c] = f2bf(acc[i][j][rr] + bs);
          }
        } else {
          const int n2 = n - 2048;
          const int h = n2 >> 7, c = n2 & 127;
          #pragma unroll
          for (int rr = 0; rr < 4; ++rr) {
            const int m = mlb + rr;
            const int bb = m >> 10, kk = m & 1023;
            out_vT[((size_t)(bb * 16 + h) * 128 + c) * 1024 + kk] = f2bf(acc[i][j][rr] + bs);
          }
        }
      } else {
        #pragma unroll
        for (int rr = 0; rr < 4; ++rr) {
          const int m = mlb + rr;
          const int bb = m >> 9;
          const float g = t_emb[((size_t)bb * 3 + 2) * 2048 + n] + ssg[2 * 2048 + n];
          out_f[(size_t)m * 2048 + n] = (acc[i][j][rr] + bs) * g;
        }
      }
    }
  }
}

// ---------------- flash attention v2: LDS-staged K/V, pre-barrier staging ----------------
// per (b,h, 64-row q tile); Q pre-scaled by 1/sqrt(C) in q-proj epilogue.
__global__ __launch_bounds__(256) void attn_kernel(
    const u16* __restrict__ qb, const u16* __restrict__ kb,
    const u16* __restrict__ vT, const int* __restrict__ k_lens,
    const int* __restrict__ q_lens, u16* __restrict__ ao)
{
  __shared__ u16 Ks[64][132];   // keys x C; stride 264B -> 2-way banks (free)
  __shared__ u16 Vs[128][68];   // c x keys; stride 136B
  __shared__ u16 Ps[64][68];    // q x keys (wave-private 16-row bands)
  const int tid  = threadIdx.x;
  const int w    = tid >> 6;
  const int lane = tid & 63;
  const int quad = lane >> 4, lq = lane & 15;
  const int bh = blockIdx.y;           // b*16 + h
  const int b  = bh >> 4;
  const int l0 = blockIdx.x * 64;
  const int kl = k_lens[b];
  const int ql = q_lens[b];

  bf16x8 qf[4];
  {
    const u16* qp = qb + ((size_t)bh * 512 + l0 + w * 16 + lq) * 128 + quad * 8;
    #pragma unroll
    for (int ks = 0; ks < 4; ++ks)
      qf[ks] = *(const bf16x8*)(qp + ks * 32);
  }

  // staging maps (coalesced global, contiguous LDS rows)
  const int krow = tid >> 4;          // 0..15, +16 per pass (4 passes)
  const int kcol = tid & 15;          // 16B chunk within 256B row
  const u16* kg = kb + ((size_t)bh * 1024 + krow) * 128 + kcol * 8;
  const int vrow = tid >> 3;          // 0..31, +32 per pass (4 passes)
  const int vcol = tid & 7;           // 16B chunk within 128B key-span
  const u16* vg = vT + (size_t)bh * 128 * 1024 + (size_t)vrow * 1024 + vcol * 8;

  f32x4 o[8];
  #pragma unroll
  for (int j = 0; j < 8; ++j) o[j] = (f32x4){0.f, 0.f, 0.f, 0.f};
  float mrun[4], lrun[4];
  #pragma unroll
  for (int rr = 0; rr < 4; ++rr) { mrun[rr] = -__builtin_inff(); lrun[rr] = 0.f; }

  const int nkt = (kl + 63) >> 6;
  for (int kt = 0; kt < nkt; ++kt) {
    const int k0 = kt * 64;
    // pre-barrier loads: in flight across the barrier, no LDS drain needed
    uint4 kd[4], vd[4];
    #pragma unroll
    for (int p = 0; p < 4; ++p)
      kd[p] = *(const uint4*)(kg + (size_t)(k0 + p * 16) * 128);
    #pragma unroll
    for (int p = 0; p < 4; ++p)
      vd[p] = *(const uint4*)(vg + (size_t)p * 32 * 1024 + k0);
    __syncthreads();                  // prior iteration's K/V reads done
    #pragma unroll
    for (int p = 0; p < 4; ++p)
      *(uint4*)&Ks[krow + p * 16][kcol * 8] = kd[p];
    #pragma unroll
    for (int p = 0; p < 4; ++p)
      *(uint4*)&Vs[vrow + p * 32][vcol * 8] = vd[p];
    __syncthreads();

    // S = Q K^T from LDS
    f32x4 s[4];
    #pragma unroll
    for (int ct = 0; ct < 4; ++ct) {
      s[ct] = (f32x4){0.f, 0.f, 0.f, 0.f};
      #pragma unroll
      for (int ks = 0; ks < 4; ++ks) {
        const bf16x8 kf = *(const bf16x8*)&Ks[ct * 16 + lq][ks * 32 + quad * 8];
        s[ct] = MFMA_BF16(qf[ks], kf, s[ct]);
      }
    }
    // key mask (Q pre-scaled)
    #pragma unroll
    for (int ct = 0; ct < 4; ++ct) {
      const bool valid = (k0 + ct * 16 + lq) < kl;
      #pragma unroll
      for (int rr = 0; rr < 4; ++rr)
        s[ct][rr] = valid ? s[ct][rr] : -__builtin_inff();
    }
    // online softmax
    float mnew[4], alpha[4], rs[4];
    #pragma unroll
    for (int rr = 0; rr < 4; ++rr) {
      float tm = fmaxf(fmaxf(s[0][rr], s[1][rr]), fmaxf(s[2][rr], s[3][rr]));
      tm = fmaxf(tm, __shfl_xor(tm, 1));
      tm = fmaxf(tm, __shfl_xor(tm, 2));
      tm = fmaxf(tm, __shfl_xor(tm, 4));
      tm = fmaxf(tm, __shfl_xor(tm, 8));
      const float mn = fmaxf(mrun[rr], tm);
      alpha[rr] = __expf(mrun[rr] - mn);
      mrun[rr] = mn;
      mnew[rr] = mn;
      rs[rr] = 0.f;
    }
    #pragma unroll
    for (int ct = 0; ct < 4; ++ct)
      #pragma unroll
      for (int rr = 0; rr < 4; ++rr) {
        const float p = __expf(s[ct][rr] - mnew[rr]);
        s[ct][rr] = p;
        rs[rr] += p;
      }
    #pragma unroll
    for (int rr = 0; rr < 4; ++rr) {
      float t = rs[rr];
      t += __shfl_xor(t, 1);
      t += __shfl_xor(t, 2);
      t += __shfl_xor(t, 4);
      t += __shfl_xor(t, 8);
      lrun[rr] = lrun[rr] * alpha[rr] + t;
    }
    #pragma unroll
    for (int j = 0; j < 8; ++j)
      #pragma unroll
      for (int rr = 0; rr < 4; ++rr)
        o[j][rr] *= alpha[rr];

    // P: C/D layout -> A layout via wave-private LDS rows
    #pragma unroll
    for (int ct = 0; ct < 4; ++ct)
      #pragma unroll
      for (int rr = 0; rr < 4; ++rr)
        Ps[w * 16 + quad * 4 + rr][ct * 16 + lq] = f2bf(s[ct][rr]);

    bf16x8 pf[2];
    pf[0] = *(const bf16x8*)&Ps[w * 16 + lq][quad * 8];
    pf[1] = *(const bf16x8*)&Ps[w * 16 + lq][32 + quad * 8];

    // O += P V from LDS
    #pragma unroll
    for (int j = 0; j < 8; ++j) {
      #pragma unroll
      for (int kk = 0; kk < 2; ++kk) {
        const bf16x8 vf = *(const bf16x8*)&Vs[j * 16 + lq][kk * 32 + quad * 8];
        o[j] = MFMA_BF16(pf[kk], vf, o[j]);
      }
    }
  }

  const int h = bh & 15;
  #pragma unroll
  for (int rr = 0; rr < 4; ++rr) {
    const int row = l0 + w * 16 + quad * 4 + rr;
    const float inv = (row < ql) ? (1.0f / lrun[rr]) : 0.0f;
    u16* op = ao + ((size_t)b * 512 + row) * 2048 + h * 128 + lq;
    #pragma unroll
    for (int j = 0; j < 8; ++j)
      op[j * 16] = f2bf(o[j][rr] * inv);
  }
}

extern "C" void kernel_launch(void* const* d_in, const int* in_sizes, int n_in,
                              void* d_out, int out_size, void* d_ws, size_t ws_size,
                              hipStream_t stream) {
  (void)in_sizes; (void)n_in; (void)out_size; (void)ws_size;
  const float* x       = (const float*)d_in[0];
  const float* latents = (const float*)d_in[1];
  const float* t_emb   = (const float*)d_in[2];
  const int*   q_lens  = (const int*)d_in[3];
  const int*   k_lens  = (const int*)d_in[4];
  const float* ln_w    = (const float*)d_in[5];
  const float* ln_b    = (const float*)d_in[6];
  const float* ssg     = (const float*)d_in[7];
  const float* Wq      = (const float*)d_in[8];
  const float* bq      = (const float*)d_in[9];
  const float* Wkv     = (const float*)d_in[10];
  const float* bkv     = (const float*)d_in[11];
  const float* Wo      = (const float*)d_in[12];
  const float* bo      = (const float*)d_in[13];
  float* out = (float*)d_out;

  u16* ws = (u16*)d_ws;
  const size_t MEG = (size_t)1 << 20;      // elements
  u16* WqT  = ws;                 //  4M elems: (2048 x 2048) bf16, N-major
  u16* WoT  = ws + 4  * MEG;      //  4M
  u16* WkvT = ws + 8  * MEG;      //  8M: (4096 x 2048)
  u16* xk   = ws + 16 * MEG;      //  8M: (B*K, 2048)
  u16* lat  = ws + 24 * MEG;      //  4M: (B*L, 2048)
  u16* qb   = ws + 28 * MEG;      //  4M: (B,H,L,C) pre-scaled
  u16* kbuf = ws + 32 * MEG;      //  8M: (B,H,K,C)
  u16* vTb  = ws + 40 * MEG;      //  8M: (B,H,C,K)
  u16* aob  = ws + 48 * MEG;      //  4M: (B*L, 2048)

  ln_fused_kernel<<<dim3(6144), dim3(256), 0, stream>>>(
      x, ln_w, ln_b, latents, t_emb, ssg, xk, lat);

  transpose_all_kernel<<<dim3(16384), dim3(256), 0, stream>>>(
      Wq, Wo, Wkv, WqT, WoT, WkvT);

  gemm_bf16_kernel<64, 0><<<dim3(16, 32), dim3(256), 0, stream>>>(
      lat, WqT, 2048, bq, qb, nullptr, nullptr, nullptr, nullptr, nullptr);
  gemm_bf16_kernel<128, 1><<<dim3(32, 32), dim3(256), 0, stream>>>(
      xk, WkvT, 2048, bkv, nullptr, kbuf, vTb, nullptr, nullptr, nullptr);

  attn_kernel<<<dim3(8, 64), dim3(256), 0, stream>>>(qb, kbuf, vTb, k_lens, q_lens, aob);

  gemm_bf16_kernel<64, 2><<<dim3(16, 32), dim3(256), 0, stream>>>(
      aob, WoT, 2048, bo, nullptr, nullptr, nullptr, out, t_emb, ssg);
}